// Round 16
// baseline (817.784 us; speedup 1.0000x reference)
//
#include <hip/hip_runtime.h>

#define NN 100000
#define NE 1600000
#define D 64
#define NL 5
#define NG 1024
#define EMBD 320
#define BN_EPS 1e-5f
#define SCAN_NB ((NN + 255) / 256)   // 391 (gbound)
#define GIN_NB ((NN + 63) / 64)      // 1563
#define SRCB 7                       // src>>14 -> 0..6
#define M2 (NN * SRCB)               // 700000 keys
#define SCAN2_NB ((M2 + 255) / 256)  // 2735

__device__ __forceinline__ unsigned short bf16rne(float f) {
  unsigned u = __float_as_uint(f);
  unsigned r = u + 0x7FFFu + ((u >> 16) & 1u);
  return (unsigned short)(r >> 16);
}
__device__ __forceinline__ float bflo(int v) {
  return __uint_as_float(((unsigned)v) << 16);
}
__device__ __forceinline__ float bfhi(int v) {
  return __uint_as_float(((unsigned)v) & 0xFFFF0000u);
}

// ---------------- fp32 -> bf16 convert (x once per call) ----------------
__global__ __launch_bounds__(256) void k_cvt(const float* __restrict__ in,
                                             unsigned short* __restrict__ outb) {
  int i = blockIdx.x * 256 + threadIdx.x;
  if (i >= NN * 16) return;
  float4 v = ((const float4*)in)[i];
  unsigned long long o = (unsigned long long)bf16rne(v.x) |
                         ((unsigned long long)bf16rne(v.y) << 16) |
                         ((unsigned long long)bf16rne(v.z) << 32) |
                         ((unsigned long long)bf16rne(v.w) << 48);
  ((unsigned long long*)outb)[i] = o;
}

// ---------------- graph boundaries from sorted batch ----------------
__global__ __launch_bounds__(256) void k_gbound(const int* __restrict__ batch,
                                                int* __restrict__ gstart) {
  int i = blockIdx.x * 256 + threadIdx.x;
  if (i >= NN) return;
  int b = batch[i];
  int bp = (i == 0) ? -1 : batch[i - 1];
  for (int g = bp + 1; g <= b; ++g) gstart[g] = i;
  if (i == NN - 1) {
    for (int g = b + 1; g <= NG; ++g) gstart[g] = NN;
  }
}

// ------- CSR build: histogram over key = dst*7 + srcblk (nt streams) ------
__global__ __launch_bounds__(256) void k_hist(const int* __restrict__ src,
                                              const int* __restrict__ dst,
                                              int* __restrict__ deg) {
  int e = blockIdx.x * 256 + threadIdx.x;
  if (e >= NE) return;
  int s = __builtin_nontemporal_load(src + e);
  int d = __builtin_nontemporal_load(dst + e);
  atomicAdd(&deg[d * SRCB + (s >> 14)], 1);
}

// ---------------- parallel exclusive scan over M2 keys, 3 phases ----------
__global__ __launch_bounds__(256) void k_scan1(const int* __restrict__ deg,
                                               int* __restrict__ bsums) {
  __shared__ int sh[256];
  int i = blockIdx.x * 256 + threadIdx.x;
  sh[threadIdx.x] = (i < M2) ? deg[i] : 0;
  __syncthreads();
  for (int off = 128; off > 0; off >>= 1) {
    if (threadIdx.x < off) sh[threadIdx.x] += sh[threadIdx.x + off];
    __syncthreads();
  }
  if (threadIdx.x == 0) bsums[blockIdx.x] = sh[0];
}

__global__ __launch_bounds__(1024) void k_scan2(int* __restrict__ bsums) {
  __shared__ int sh[1024];
  int t = threadIdx.x;
  int loc[3];
  int s = 0;
#pragma unroll
  for (int i = 0; i < 3; ++i) {
    int idx = t * 3 + i;
    loc[i] = s;
    if (idx < SCAN2_NB) s += bsums[idx];
  }
  sh[t] = s;
  __syncthreads();
  for (int off = 1; off < 1024; off <<= 1) {
    int u = (t >= off) ? sh[t - off] : 0;
    __syncthreads();
    sh[t] += u;
    __syncthreads();
  }
  int base = sh[t] - s;  // exclusive over thread chunks
#pragma unroll
  for (int i = 0; i < 3; ++i) {
    int idx = t * 3 + i;
    if (idx < SCAN2_NB) bsums[idx] = base + loc[i];
  }
}

__global__ __launch_bounds__(256) void k_scan3(int* __restrict__ row_ptr,
                                               int* __restrict__ cursor,
                                               const int* __restrict__ bsums) {
  __shared__ int sh[256];
  int t = threadIdx.x;
  int i = blockIdx.x * 256 + t;
  int v = (i < M2) ? row_ptr[i] : 0;
  sh[t] = v;
  __syncthreads();
  for (int off = 1; off < 256; off <<= 1) {
    int u = (t >= off) ? sh[t - off] : 0;
    __syncthreads();
    sh[t] += u;
    __syncthreads();
  }
  int excl = sh[t] - v + bsums[blockIdx.x];
  if (i < M2) {
    row_ptr[i] = excl;
    cursor[i] = excl;
    if (i == M2 - 1) row_ptr[M2] = excl + v;
  }
}

// -------- fill CSR (src-blocked keys): 8B pair per edge, NT store ---------
__global__ __launch_bounds__(256) void k_fill(const int* __restrict__ src,
                                              const int* __restrict__ dst,
                                              const float* __restrict__ w,
                                              int* __restrict__ cursor,
                                              long long* __restrict__ epair) {
  int e = blockIdx.x * 256 + threadIdx.x;
  if (e >= NE) return;
  int s = __builtin_nontemporal_load(src + e);
  int d = __builtin_nontemporal_load(dst + e);
  float we = __builtin_nontemporal_load(w + e);
  int slot = atomicAdd(&cursor[d * SRCB + (s >> 14)], 1);
  long long p = (long long)(unsigned)s |
                ((long long)(unsigned)__float_as_int(we) << 32);
  __builtin_nontemporal_store(p, epair + slot);
}

// ---- fused gather(bf16) + deferred-BN + GIN MLP + BN-stats, bf16-only ----
#define ACC8(CA, CB, WE)                                                      \
  a0.x = fmaf(bflo(CA.x), WE, a0.x); a0.y = fmaf(bfhi(CA.x), WE, a0.y);       \
  a0.z = fmaf(bflo(CA.y), WE, a0.z); a0.w = fmaf(bfhi(CA.y), WE, a0.w);       \
  a1.x = fmaf(bflo(CA.z), WE, a1.x); a1.y = fmaf(bfhi(CA.z), WE, a1.y);       \
  a1.z = fmaf(bflo(CA.w), WE, a1.z); a1.w = fmaf(bfhi(CA.w), WE, a1.w);       \
  a2.x = fmaf(bflo(CB.x), WE, a2.x); a2.y = fmaf(bfhi(CB.x), WE, a2.y);       \
  a2.z = fmaf(bflo(CB.y), WE, a2.z); a2.w = fmaf(bfhi(CB.y), WE, a2.w);       \
  a3.x = fmaf(bflo(CB.z), WE, a3.x); a3.y = fmaf(bfhi(CB.z), WE, a3.y);       \
  a3.z = fmaf(bflo(CB.w), WE, a3.z); a3.w = fmaf(bfhi(CB.w), WE, a3.w);

__global__ __launch_bounds__(256, 6) void k_gin(const float* __restrict__ x0,
                                                const unsigned short* __restrict__ hbf,
                                                unsigned short* __restrict__ gbf,
                                                const int* __restrict__ row_ptr,
                                                const long long* __restrict__ epair,
                                                const float* __restrict__ W1,
                                                const float* __restrict__ b1,
                                                const float* __restrict__ W2,
                                                const float* __restrict__ b2,
                                                const float* __restrict__ statsP,
                                                const float* __restrict__ gammaP,
                                                const float* __restrict__ betaP,
                                                int first,
                                                float* __restrict__ statsL) {
  __shared__ float zin[64 * 65];   // also stats scratch at the end
  __shared__ float sW[32 * 64];    // half of one weight matrix
  __shared__ float sb[64];
  __shared__ float wsumS[64];
  __shared__ float scA[64], sbA[64];
  const int t = threadIdx.x;
  const int nb = blockIdx.x * 64;
  const int nr = t >> 4, fc = t & 15;

  // stage W1 rows 0..31, b1; prev-layer affine coeffs
  for (int i = t; i < 2048; i += 256) sW[i] = W1[i];
  if (t < 64) {
    sb[t] = b1[t];
    if (!first) {
      float m = statsP[t] * (1.f / NN);
      float v = fmaxf(statsP[64 + t] * (1.f / NN) - m * m, 0.f);
      float sc = gammaP[t] * rsqrtf(v + BN_EPS);
      scA[t] = sc;
      sbA[t] = betaP[t] - m * sc;
    }
  }

  // staging: bf16 gather (unroll 2, nt epair) + own term -> zin
  {
    const int nl = t >> 2;        // 0..63 local node
    const int q = t & 3;          // quarter of the row (16 cols)
    const int n = nb + nl;
    float4 a0 = {0.f, 0.f, 0.f, 0.f}, a1 = a0, a2 = a0, a3 = a0;
    float wsum = 0.f;
    if (n < NN) {
      const int beg = row_ptr[n * SRCB], end = row_ptr[n * SRCB + SRCB];
      int i = beg;
      for (; i + 2 <= end; i += 2) {
        long long e0 = __builtin_nontemporal_load(epair + i);
        long long e1 = __builtin_nontemporal_load(epair + i + 1);
        int s0 = (int)(e0 & 0xFFFFFFFFll);
        float w0 = __int_as_float((int)(e0 >> 32));
        int s1 = (int)(e1 & 0xFFFFFFFFll);
        float w1 = __int_as_float((int)(e1 >> 32));
        const int4* p0 = (const int4*)(hbf + (size_t)s0 * D);
        const int4* p1 = (const int4*)(hbf + (size_t)s1 * D);
        int4 r0a = p0[2 * q], r0b = p0[2 * q + 1];
        int4 r1a = p1[2 * q], r1b = p1[2 * q + 1];
        ACC8(r0a, r0b, w0)
        wsum += w0;
        ACC8(r1a, r1b, w1)
        wsum += w1;
      }
      for (; i < end; ++i) {
        long long e0 = __builtin_nontemporal_load(epair + i);
        int s0 = (int)(e0 & 0xFFFFFFFFll);
        float w0 = __int_as_float((int)(e0 >> 32));
        const int4* p0 = (const int4*)(hbf + (size_t)s0 * D);
        int4 r0a = p0[2 * q], r0b = p0[2 * q + 1];
        ACC8(r0a, r0b, w0)
        wsum += w0;
      }
      // own term: fp32 x for layer 0 (single pass), bf16 after
      if (first) {
        const float4* own = (const float4*)(x0 + (size_t)n * D) + q * 4;
        float4 o0 = own[0], o1 = own[1], o2 = own[2], o3 = own[3];
        a0.x += o0.x; a0.y += o0.y; a0.z += o0.z; a0.w += o0.w;
        a1.x += o1.x; a1.y += o1.y; a1.z += o1.z; a1.w += o1.w;
        a2.x += o2.x; a2.y += o2.y; a2.z += o2.z; a2.w += o2.w;
        a3.x += o3.x; a3.y += o3.y; a3.z += o3.z; a3.w += o3.w;
      } else {
        const int4* hp = (const int4*)(hbf + (size_t)n * D);
        int4 c0 = hp[2 * q], c1 = hp[2 * q + 1];
        a0.x += bflo(c0.x); a0.y += bfhi(c0.x);
        a0.z += bflo(c0.y); a0.w += bfhi(c0.y);
        a1.x += bflo(c0.z); a1.y += bfhi(c0.z);
        a1.z += bflo(c0.w); a1.w += bfhi(c0.w);
        a2.x += bflo(c1.x); a2.y += bfhi(c1.x);
        a2.z += bflo(c1.y); a2.w += bfhi(c1.y);
        a3.x += bflo(c1.z); a3.y += bfhi(c1.z);
        a3.z += bflo(c1.w); a3.w += bfhi(c1.w);
      }
    }
    float* zr = &zin[nl * 65 + q * 16];
    *(float4*)(zr + 0) = a0;
    *(float4*)(zr + 4) = a1;
    *(float4*)(zr + 8) = a2;
    *(float4*)(zr + 12) = a3;
    if (q == 0) wsumS[nl] = wsum;
  }
  __syncthreads();

  // deferred-BN affine pass over the z-tile
  if (!first) {
#pragma unroll
    for (int pass = 0; pass < 4; ++pass) {
      int idx = pass * 1024 + t * 4;
      int r = idx >> 6, c = idx & 63;
      float wp1 = 1.f + wsumS[r];
      float4 z = *(float4*)&zin[r * 65 + c];
      z.x = fmaf(z.x, scA[c + 0], sbA[c + 0] * wp1);
      z.y = fmaf(z.y, scA[c + 1], sbA[c + 1] * wp1);
      z.z = fmaf(z.z, scA[c + 2], sbA[c + 2] * wp1);
      z.w = fmaf(z.w, scA[c + 3], sbA[c + 3] * wp1);
      *(float4*)&zin[r * 65 + c] = z;
    }
    __syncthreads();
  }

#define GEMM_HALF(ACC, KBASE)                                                 \
  _Pragma("unroll 2") for (int kc = 0; kc < 8; ++kc) {                        \
    float4 zv[4], wv[4];                                                      \
    _Pragma("unroll") for (int i = 0; i < 4; ++i)                             \
        zv[i] = *(float4*)&zin[(nr * 4 + i) * 65 + ((KBASE) + kc) * 4];       \
    _Pragma("unroll") for (int kk = 0; kk < 4; ++kk)                          \
        wv[kk] = *(float4*)&sW[(kc * 4 + kk) * 64 + fc * 4];                  \
    _Pragma("unroll") for (int i = 0; i < 4; ++i) {                           \
      ACC[i].x = fmaf(zv[i].x, wv[0].x, ACC[i].x);                            \
      ACC[i].y = fmaf(zv[i].x, wv[0].y, ACC[i].y);                            \
      ACC[i].z = fmaf(zv[i].x, wv[0].z, ACC[i].z);                            \
      ACC[i].w = fmaf(zv[i].x, wv[0].w, ACC[i].w);                            \
      ACC[i].x = fmaf(zv[i].y, wv[1].x, ACC[i].x);                            \
      ACC[i].y = fmaf(zv[i].y, wv[1].y, ACC[i].y);                            \
      ACC[i].z = fmaf(zv[i].y, wv[1].z, ACC[i].z);                            \
      ACC[i].w = fmaf(zv[i].y, wv[1].w, ACC[i].w);                            \
      ACC[i].x = fmaf(zv[i].z, wv[2].x, ACC[i].x);                            \
      ACC[i].y = fmaf(zv[i].z, wv[2].y, ACC[i].y);                            \
      ACC[i].z = fmaf(zv[i].z, wv[2].z, ACC[i].z);                            \
      ACC[i].w = fmaf(zv[i].z, wv[2].w, ACC[i].w);                            \
      ACC[i].x = fmaf(zv[i].w, wv[3].x, ACC[i].x);                            \
      ACC[i].y = fmaf(zv[i].w, wv[3].y, ACC[i].y);                            \
      ACC[i].z = fmaf(zv[i].w, wv[3].z, ACC[i].z);                            \
      ACC[i].w = fmaf(zv[i].w, wv[3].w, ACC[i].w);                            \
    }                                                                         \
  }

#define RELU4(ACC)                                                            \
  _Pragma("unroll") for (int i = 0; i < 4; ++i) {                             \
    ACC[i].x = fmaxf(ACC[i].x, 0.f);                                          \
    ACC[i].y = fmaxf(ACC[i].y, 0.f);                                          \
    ACC[i].z = fmaxf(ACC[i].z, 0.f);                                          \
    ACC[i].w = fmaxf(ACC[i].w, 0.f);                                          \
  }

  // ---- GEMM1 ----
  float4 acc[4];
  {
    float4 bias = *(float4*)&sb[fc * 4];
#pragma unroll
    for (int i = 0; i < 4; ++i) acc[i] = bias;
  }
  GEMM_HALF(acc, 0)
  __syncthreads();
  for (int i = t; i < 2048; i += 256) sW[i] = W1[2048 + i];
  __syncthreads();
  GEMM_HALF(acc, 8)
  RELU4(acc)
  __syncthreads();

  // write intermediate, stage W2 rows 0..31 + b2
#pragma unroll
  for (int i = 0; i < 4; ++i) *(float4*)&zin[(nr * 4 + i) * 65 + fc * 4] = acc[i];
  for (int i = t; i < 2048; i += 256) sW[i] = W2[i];
  if (t < 64) sb[t] = b2[t];
  __syncthreads();

  // ---- GEMM2 ----
  float4 acc2[4];
  {
    float4 bias = *(float4*)&sb[fc * 4];
#pragma unroll
    for (int i = 0; i < 4; ++i) acc2[i] = bias;
  }
  GEMM_HALF(acc2, 0)
  __syncthreads();
  for (int i = t; i < 2048; i += 256) sW[i] = W2[2048 + i];
  __syncthreads();
  GEMM_HALF(acc2, 8)
  RELU4(acc2)

  // bf16 NT store + masked stats partials (fp32, pre-quantization)
  float4 s4 = {0.f, 0.f, 0.f, 0.f}, q4 = {0.f, 0.f, 0.f, 0.f};
#pragma unroll
  for (int i = 0; i < 4; ++i) {
    int n = nb + nr * 4 + i;
    if (n < NN) {
      unsigned long long ob = (unsigned long long)bf16rne(acc2[i].x) |
                              ((unsigned long long)bf16rne(acc2[i].y) << 16) |
                              ((unsigned long long)bf16rne(acc2[i].z) << 32) |
                              ((unsigned long long)bf16rne(acc2[i].w) << 48);
      __builtin_nontemporal_store(
          ob, (unsigned long long*)(gbf + (size_t)n * D + fc * 4));
      s4.x += acc2[i].x; s4.y += acc2[i].y; s4.z += acc2[i].z; s4.w += acc2[i].w;
      q4.x = fmaf(acc2[i].x, acc2[i].x, q4.x);
      q4.y = fmaf(acc2[i].y, acc2[i].y, q4.y);
      q4.z = fmaf(acc2[i].z, acc2[i].z, q4.z);
      q4.w = fmaf(acc2[i].w, acc2[i].w, q4.w);
    }
  }
#pragma unroll
  for (int m = 16; m <= 32; m <<= 1) {
    s4.x += __shfl_xor(s4.x, m, 64); s4.y += __shfl_xor(s4.y, m, 64);
    s4.z += __shfl_xor(s4.z, m, 64); s4.w += __shfl_xor(s4.w, m, 64);
    q4.x += __shfl_xor(q4.x, m, 64); q4.y += __shfl_xor(q4.y, m, 64);
    q4.z += __shfl_xor(q4.z, m, 64); q4.w += __shfl_xor(q4.w, m, 64);
  }
  __syncthreads();  // all zin reads done -> safe to alias stats scratch
  int wv_ = t >> 6;
  if ((t & 63) < 16) {
    *(float4*)&zin[wv_ * 64 + fc * 4] = s4;        // sSf = zin[0..255]
    *(float4*)&zin[256 + wv_ * 64 + fc * 4] = q4;  // sQf = zin[256..511]
  }
  __syncthreads();
  if (t < 64) {
    float S = zin[t] + zin[64 + t] + zin[128 + t] + zin[192 + t];
    float Q = zin[256 + t] + zin[320 + t] + zin[384 + t] + zin[448 + t];
    unsafeAtomicAdd(&statsL[t], S);
    unsafeAtomicAdd(&statsL[64 + t], Q);
  }
#undef GEMM_HALF
#undef RELU4
}

// ---------------- per-graph raw mean pool (bf16 read-only) ----------------
__global__ __launch_bounds__(256) void k_poolraw(const unsigned short* __restrict__ gbf,
                                                 const int* __restrict__ gstart,
                                                 float* __restrict__ pooledraw,
                                                 int layer) {
  __shared__ float4 sh4[256];
  int g = blockIdx.x;
  int beg = gstart[g], end = gstart[g + 1];
  int p = threadIdx.x & 15, r = threadIdx.x >> 4;
  float4 s = {0.f, 0.f, 0.f, 0.f};
  for (int n = beg + r; n < end; n += 16) {
    int2 c = ((const int2*)(gbf + (size_t)n * D))[p];
    s.x += bflo(c.x); s.y += bfhi(c.x);
    s.z += bflo(c.y); s.w += bfhi(c.y);
  }
  sh4[threadIdx.x] = s;
  __syncthreads();
  if (threadIdx.x < 16) {
    float4 tot = {0.f, 0.f, 0.f, 0.f};
#pragma unroll
    for (int j = 0; j < 16; ++j) {
      float4 u = sh4[j * 16 + threadIdx.x];
      tot.x += u.x; tot.y += u.y; tot.z += u.z; tot.w += u.w;
    }
    int cnt = end - beg;
    float inv = 1.0f / (float)(cnt > 1 ? cnt : 1);
    float4 o = {tot.x * inv, tot.y * inv, tot.z * inv, tot.w * inv};
    ((float4*)(pooledraw + (size_t)g * EMBD + layer * D))[threadIdx.x] = o;
  }
}

// ------- projection head (applies all 5 layers' BN affine on load) --------
__global__ __launch_bounds__(EMBD) void k_proj(const float* __restrict__ pooledraw,
                                               const float* __restrict__ stats,
                                               const float* __restrict__ gammas,
                                               const float* __restrict__ betas,
                                               const float* __restrict__ pW1,
                                               const float* __restrict__ pb1,
                                               const float* __restrict__ pW2,
                                               const float* __restrict__ pb2,
                                               float* __restrict__ out) {
  __shared__ float row[EMBD];
  __shared__ float y1[EMBD];
  int g = blockIdx.x, j = threadIdx.x;
  {
    int L = j >> 6, f = j & 63;
    float m = stats[L * 128 + f] * (1.f / NN);
    float v = fmaxf(stats[L * 128 + 64 + f] * (1.f / NN) - m * m, 0.f);
    float sc = gammas[L * D + f] * rsqrtf(v + BN_EPS);
    float sb = betas[L * D + f] - m * sc;
    row[j] = fmaf(pooledraw[(size_t)g * EMBD + j], sc, sb);
  }
  __syncthreads();
  float acc = pb1[j];
#pragma unroll 4
  for (int k = 0; k < EMBD; ++k) acc = fmaf(row[k], pW1[(size_t)k * EMBD + j], acc);
  y1[j] = fmaxf(acc, 0.f);
  __syncthreads();
  acc = pb2[j];
#pragma unroll 4
  for (int k = 0; k < EMBD; ++k) acc = fmaf(y1[k], pW2[(size_t)k * EMBD + j], acc);
  out[(size_t)g * EMBD + j] = acc;
}

extern "C" void kernel_launch(void* const* d_in, const int* in_sizes, int n_in,
                              void* d_out, int out_size, void* d_ws, size_t ws_size,
                              hipStream_t stream) {
  const float* x = (const float*)d_in[0];
  const int* ei = (const int*)d_in[1];
  const float* ew = (const float*)d_in[2];
  const int* batch = (const int*)d_in[3];
  const float* W1s = (const float*)d_in[4];
  const float* b1s = (const float*)d_in[5];
  const float* W2s = (const float*)d_in[6];
  const float* b2s = (const float*)d_in[7];
  const float* gammas = (const float*)d_in[8];
  const float* betas = (const float*)d_in[9];
  const float* pW1 = (const float*)d_in[10];
  const float* pb1 = (const float*)d_in[11];
  const float* pW2 = (const float*)d_in[12];
  const float* pb2 = (const float*)d_in[13];
  const int* srcv = ei;
  const int* dstv = ei + NE;

  char* ws = (char*)d_ws;
  float* stats = (float*)ws;                             // NL*128
  float* pooledraw = stats + NL * 128;                   // NG*EMBD
  int* gstart = (int*)(pooledraw + (size_t)NG * EMBD);   // NG+1
  int* row_ptr = gstart + NG + 1;                        // M2+1 (deg then scan)
  int* cursor = row_ptr + M2 + 1;                        // M2
  long long* epair = (long long*)(cursor + M2);          // NE (8B each)
  int* bsums = (int*)(epair + NE);                       // SCAN2_NB
  unsigned short* hbfA = (unsigned short*)(bsums + SCAN2_NB);  // NN*D bf16
  unsigned short* hbfB = hbfA + (size_t)NN * D;               // NN*D bf16

  // ---- CSR build (src-blocked) + graph bounds + stats zero + x->bf16 ----
  hipMemsetAsync(row_ptr, 0, (M2 + 1) * sizeof(int), stream);
  hipMemsetAsync(stats, 0, NL * 128 * sizeof(float), stream);
  k_hist<<<(NE + 255) / 256, 256, 0, stream>>>(srcv, dstv, row_ptr);
  k_scan1<<<SCAN2_NB, 256, 0, stream>>>(row_ptr, bsums);
  k_scan2<<<1, 1024, 0, stream>>>(bsums);
  k_scan3<<<SCAN2_NB, 256, 0, stream>>>(row_ptr, cursor, bsums);
  k_fill<<<(NE + 255) / 256, 256, 0, stream>>>(srcv, dstv, ew, cursor, epair);
  k_gbound<<<SCAN_NB, 256, 0, stream>>>(batch, gstart);
  k_cvt<<<(NN * 16 + 255) / 256, 256, 0, stream>>>(x, hbfA);

  unsigned short* bfin = hbfA;
  unsigned short* bfout = hbfB;
  for (int L = 0; L < NL; ++L) {
    k_gin<<<GIN_NB, 256, 0, stream>>>(x, bfin, bfout, row_ptr, epair,
                                      W1s + L * D * D, b1s + L * D,
                                      W2s + L * D * D, b2s + L * D,
                                      stats + (L > 0 ? (L - 1) * 128 : 0),
                                      gammas + (L > 0 ? (L - 1) * D : 0),
                                      betas + (L > 0 ? (L - 1) * D : 0),
                                      L == 0 ? 1 : 0,
                                      stats + L * 128);
    k_poolraw<<<NG, 256, 0, stream>>>(bfout, gstart, pooledraw, L);
    unsigned short* tmpb = bfin;
    bfin = bfout;
    bfout = tmpb;
  }
  k_proj<<<NG, EMBD, 0, stream>>>(pooledraw, stats, gammas, betas,
                                  pW1, pb1, pW2, pb2, (float*)d_out);
}

// Round 17
// 797.922 us; speedup vs baseline: 1.0249x; 1.0249x over previous
//
#include <hip/hip_runtime.h>

#define NN 100000
#define NE 1600000
#define D 64
#define NL 5
#define NG 1024
#define EMBD 320
#define BN_EPS 1e-5f
#define SCAN_NB ((NN + 255) / 256)   // 391 (gbound)
#define GIN_NB ((NN + 63) / 64)      // 1563
#define SRCB 7                       // src>>14 -> 0..6
#define M2 (NN * SRCB)               // 700000 keys
#define SCAN2_NB ((M2 + 255) / 256)  // 2735

__device__ __forceinline__ unsigned short bf16rne(float f) {
  unsigned u = __float_as_uint(f);
  unsigned r = u + 0x7FFFu + ((u >> 16) & 1u);
  return (unsigned short)(r >> 16);
}
__device__ __forceinline__ float bflo(int v) {
  return __uint_as_float(((unsigned)v) << 16);
}
__device__ __forceinline__ float bfhi(int v) {
  return __uint_as_float(((unsigned)v) & 0xFFFF0000u);
}

// ---------------- fp32 -> bf16 convert (x once per call) ----------------
__global__ __launch_bounds__(256) void k_cvt(const float* __restrict__ in,
                                             unsigned short* __restrict__ outb) {
  int i = blockIdx.x * 256 + threadIdx.x;
  if (i >= NN * 16) return;
  float4 v = ((const float4*)in)[i];
  ushort4 o;
  o.x = bf16rne(v.x); o.y = bf16rne(v.y); o.z = bf16rne(v.z); o.w = bf16rne(v.w);
  ((ushort4*)outb)[i] = o;
}

// ---------------- graph boundaries from sorted batch ----------------
__global__ __launch_bounds__(256) void k_gbound(const int* __restrict__ batch,
                                                int* __restrict__ gstart) {
  int i = blockIdx.x * 256 + threadIdx.x;
  if (i >= NN) return;
  int b = batch[i];
  int bp = (i == 0) ? -1 : batch[i - 1];
  for (int g = bp + 1; g <= b; ++g) gstart[g] = i;
  if (i == NN - 1) {
    for (int g = b + 1; g <= NG; ++g) gstart[g] = NN;
  }
}

// ------- CSR build: histogram over key = dst*7 + srcblk (nt streams) ------
__global__ __launch_bounds__(256) void k_hist(const int* __restrict__ src,
                                              const int* __restrict__ dst,
                                              int* __restrict__ deg) {
  int e = blockIdx.x * 256 + threadIdx.x;
  if (e >= NE) return;
  int s = __builtin_nontemporal_load(src + e);
  int d = __builtin_nontemporal_load(dst + e);
  atomicAdd(&deg[d * SRCB + (s >> 14)], 1);
}

// ---------------- parallel exclusive scan over M2 keys, 3 phases ----------
__global__ __launch_bounds__(256) void k_scan1(const int* __restrict__ deg,
                                               int* __restrict__ bsums) {
  __shared__ int sh[256];
  int i = blockIdx.x * 256 + threadIdx.x;
  sh[threadIdx.x] = (i < M2) ? deg[i] : 0;
  __syncthreads();
  for (int off = 128; off > 0; off >>= 1) {
    if (threadIdx.x < off) sh[threadIdx.x] += sh[threadIdx.x + off];
    __syncthreads();
  }
  if (threadIdx.x == 0) bsums[blockIdx.x] = sh[0];
}

__global__ __launch_bounds__(1024) void k_scan2(int* __restrict__ bsums) {
  __shared__ int sh[1024];
  int t = threadIdx.x;
  int loc[3];
  int s = 0;
#pragma unroll
  for (int i = 0; i < 3; ++i) {
    int idx = t * 3 + i;
    loc[i] = s;
    if (idx < SCAN2_NB) s += bsums[idx];
  }
  sh[t] = s;
  __syncthreads();
  for (int off = 1; off < 1024; off <<= 1) {
    int u = (t >= off) ? sh[t - off] : 0;
    __syncthreads();
    sh[t] += u;
    __syncthreads();
  }
  int base = sh[t] - s;  // exclusive over thread chunks
#pragma unroll
  for (int i = 0; i < 3; ++i) {
    int idx = t * 3 + i;
    if (idx < SCAN2_NB) bsums[idx] = base + loc[i];
  }
}

__global__ __launch_bounds__(256) void k_scan3(int* __restrict__ row_ptr,
                                               int* __restrict__ cursor,
                                               const int* __restrict__ bsums) {
  __shared__ int sh[256];
  int t = threadIdx.x;
  int i = blockIdx.x * 256 + t;
  int v = (i < M2) ? row_ptr[i] : 0;
  sh[t] = v;
  __syncthreads();
  for (int off = 1; off < 256; off <<= 1) {
    int u = (t >= off) ? sh[t - off] : 0;
    __syncthreads();
    sh[t] += u;
    __syncthreads();
  }
  int excl = sh[t] - v + bsums[blockIdx.x];
  if (i < M2) {
    row_ptr[i] = excl;
    cursor[i] = excl;
    if (i == M2 - 1) row_ptr[M2] = excl + v;
  }
}

// -------- fill CSR (src-blocked keys): 8B pair per edge -------------------
__global__ __launch_bounds__(256) void k_fill(const int* __restrict__ src,
                                              const int* __restrict__ dst,
                                              const float* __restrict__ w,
                                              int* __restrict__ cursor,
                                              long long* __restrict__ epair) {
  int e = blockIdx.x * 256 + threadIdx.x;
  if (e >= NE) return;
  int s = __builtin_nontemporal_load(src + e);
  int d = __builtin_nontemporal_load(dst + e);
  float we = __builtin_nontemporal_load(w + e);
  int slot = atomicAdd(&cursor[d * SRCB + (s >> 14)], 1);
  long long p = (long long)(unsigned)s |
                ((long long)(unsigned)__float_as_int(we) << 32);
  epair[slot] = p;
}

// ---- fused gather(bf16) + deferred-BN + GIN MLP + BN-stats + pooling -----
#define ACC8(CA, CB, WE)                                                      \
  a0.x = fmaf(bflo(CA.x), WE, a0.x); a0.y = fmaf(bfhi(CA.x), WE, a0.y);       \
  a0.z = fmaf(bflo(CA.y), WE, a0.z); a0.w = fmaf(bfhi(CA.y), WE, a0.w);       \
  a1.x = fmaf(bflo(CA.z), WE, a1.x); a1.y = fmaf(bfhi(CA.z), WE, a1.y);       \
  a1.z = fmaf(bflo(CA.w), WE, a1.z); a1.w = fmaf(bfhi(CA.w), WE, a1.w);       \
  a2.x = fmaf(bflo(CB.x), WE, a2.x); a2.y = fmaf(bfhi(CB.x), WE, a2.y);       \
  a2.z = fmaf(bflo(CB.y), WE, a2.z); a2.w = fmaf(bfhi(CB.y), WE, a2.w);       \
  a3.x = fmaf(bflo(CB.z), WE, a3.x); a3.y = fmaf(bfhi(CB.z), WE, a3.y);       \
  a3.z = fmaf(bflo(CB.w), WE, a3.z); a3.w = fmaf(bfhi(CB.w), WE, a3.w);

__global__ __launch_bounds__(256, 6) void k_gin(const float* __restrict__ x0,
                                                const unsigned short* __restrict__ hbf,
                                                unsigned short* __restrict__ gbf,
                                                const int* __restrict__ row_ptr,
                                                const long long* __restrict__ epair,
                                                const int* __restrict__ batch_,
                                                const int* __restrict__ gstart_,
                                                float* __restrict__ pooledraw,
                                                int layer,
                                                const float* __restrict__ W1,
                                                const float* __restrict__ b1,
                                                const float* __restrict__ W2,
                                                const float* __restrict__ b2,
                                                const float* __restrict__ statsP,
                                                const float* __restrict__ gammaP,
                                                const float* __restrict__ betaP,
                                                int first,
                                                float* __restrict__ statsL) {
  __shared__ float zin[64 * 65];   // z-tile, then output tile, then stats scratch
  __shared__ float sW[32 * 64];    // half of one weight matrix
  __shared__ float sb[64];
  __shared__ float wsumS[64];
  __shared__ float scA[64], sbA[64];
  __shared__ float psum[256];
  const int t = threadIdx.x;
  const int nb = blockIdx.x * 64;
  const int nr = t >> 4, fc = t & 15;

  // stage W1 rows 0..31, b1; prev-layer affine coeffs
  for (int i = t; i < 2048; i += 256) sW[i] = W1[i];
  if (t < 64) {
    sb[t] = b1[t];
    if (!first) {
      float m = statsP[t] * (1.f / NN);
      float v = fmaxf(statsP[64 + t] * (1.f / NN) - m * m, 0.f);
      float sc = gammaP[t] * rsqrtf(v + BN_EPS);
      scA[t] = sc;
      sbA[t] = betaP[t] - m * sc;
    }
  }

  // staging: bf16 gather (unroll 2, nt epair) + own term -> zin
  {
    const int nl = t >> 2;        // 0..63 local node
    const int q = t & 3;          // quarter of the row (16 cols)
    const int n = nb + nl;
    float4 a0 = {0.f, 0.f, 0.f, 0.f}, a1 = a0, a2 = a0, a3 = a0;
    float wsum = 0.f;
    if (n < NN) {
      const int beg = row_ptr[n * SRCB], end = row_ptr[n * SRCB + SRCB];
      int i = beg;
      for (; i + 2 <= end; i += 2) {
        long long e0 = __builtin_nontemporal_load(epair + i);
        long long e1 = __builtin_nontemporal_load(epair + i + 1);
        int s0 = (int)(e0 & 0xFFFFFFFFll);
        float w0 = __int_as_float((int)(e0 >> 32));
        int s1 = (int)(e1 & 0xFFFFFFFFll);
        float w1 = __int_as_float((int)(e1 >> 32));
        const int4* p0 = (const int4*)(hbf + (size_t)s0 * D);
        const int4* p1 = (const int4*)(hbf + (size_t)s1 * D);
        int4 r0a = p0[2 * q], r0b = p0[2 * q + 1];
        int4 r1a = p1[2 * q], r1b = p1[2 * q + 1];
        ACC8(r0a, r0b, w0)
        wsum += w0;
        ACC8(r1a, r1b, w1)
        wsum += w1;
      }
      for (; i < end; ++i) {
        long long e0 = __builtin_nontemporal_load(epair + i);
        int s0 = (int)(e0 & 0xFFFFFFFFll);
        float w0 = __int_as_float((int)(e0 >> 32));
        const int4* p0 = (const int4*)(hbf + (size_t)s0 * D);
        int4 r0a = p0[2 * q], r0b = p0[2 * q + 1];
        ACC8(r0a, r0b, w0)
        wsum += w0;
      }
      // own term: fp32 x for layer 0 (single pass), bf16 after
      if (first) {
        const float4* own = (const float4*)(x0 + (size_t)n * D) + q * 4;
        float4 o0 = own[0], o1 = own[1], o2 = own[2], o3 = own[3];
        a0.x += o0.x; a0.y += o0.y; a0.z += o0.z; a0.w += o0.w;
        a1.x += o1.x; a1.y += o1.y; a1.z += o1.z; a1.w += o1.w;
        a2.x += o2.x; a2.y += o2.y; a2.z += o2.z; a2.w += o2.w;
        a3.x += o3.x; a3.y += o3.y; a3.z += o3.z; a3.w += o3.w;
      } else {
        const int4* hp = (const int4*)(hbf + (size_t)n * D);
        int4 c0 = hp[2 * q], c1 = hp[2 * q + 1];
        a0.x += bflo(c0.x); a0.y += bfhi(c0.x);
        a0.z += bflo(c0.y); a0.w += bfhi(c0.y);
        a1.x += bflo(c0.z); a1.y += bfhi(c0.z);
        a1.z += bflo(c0.w); a1.w += bfhi(c0.w);
        a2.x += bflo(c1.x); a2.y += bfhi(c1.x);
        a2.z += bflo(c1.y); a2.w += bfhi(c1.y);
        a3.x += bflo(c1.z); a3.y += bfhi(c1.z);
        a3.z += bflo(c1.w); a3.w += bfhi(c1.w);
      }
    }
    float* zr = &zin[nl * 65 + q * 16];
    *(float4*)(zr + 0) = a0;
    *(float4*)(zr + 4) = a1;
    *(float4*)(zr + 8) = a2;
    *(float4*)(zr + 12) = a3;
    if (q == 0) wsumS[nl] = wsum;
  }
  __syncthreads();

  // deferred-BN affine pass over the z-tile
  if (!first) {
#pragma unroll
    for (int pass = 0; pass < 4; ++pass) {
      int idx = pass * 1024 + t * 4;
      int r = idx >> 6, c = idx & 63;
      float wp1 = 1.f + wsumS[r];
      float4 z = *(float4*)&zin[r * 65 + c];
      z.x = fmaf(z.x, scA[c + 0], sbA[c + 0] * wp1);
      z.y = fmaf(z.y, scA[c + 1], sbA[c + 1] * wp1);
      z.z = fmaf(z.z, scA[c + 2], sbA[c + 2] * wp1);
      z.w = fmaf(z.w, scA[c + 3], sbA[c + 3] * wp1);
      *(float4*)&zin[r * 65 + c] = z;
    }
    __syncthreads();
  }

#define GEMM_HALF(ACC, KBASE)                                                 \
  _Pragma("unroll 2") for (int kc = 0; kc < 8; ++kc) {                        \
    float4 zv[4], wv[4];                                                      \
    _Pragma("unroll") for (int i = 0; i < 4; ++i)                             \
        zv[i] = *(float4*)&zin[(nr * 4 + i) * 65 + ((KBASE) + kc) * 4];       \
    _Pragma("unroll") for (int kk = 0; kk < 4; ++kk)                          \
        wv[kk] = *(float4*)&sW[(kc * 4 + kk) * 64 + fc * 4];                  \
    _Pragma("unroll") for (int i = 0; i < 4; ++i) {                           \
      ACC[i].x = fmaf(zv[i].x, wv[0].x, ACC[i].x);                            \
      ACC[i].y = fmaf(zv[i].x, wv[0].y, ACC[i].y);                            \
      ACC[i].z = fmaf(zv[i].x, wv[0].z, ACC[i].z);                            \
      ACC[i].w = fmaf(zv[i].x, wv[0].w, ACC[i].w);                            \
      ACC[i].x = fmaf(zv[i].y, wv[1].x, ACC[i].x);                            \
      ACC[i].y = fmaf(zv[i].y, wv[1].y, ACC[i].y);                            \
      ACC[i].z = fmaf(zv[i].y, wv[1].z, ACC[i].z);                            \
      ACC[i].w = fmaf(zv[i].y, wv[1].w, ACC[i].w);                            \
      ACC[i].x = fmaf(zv[i].z, wv[2].x, ACC[i].x);                            \
      ACC[i].y = fmaf(zv[i].z, wv[2].y, ACC[i].y);                            \
      ACC[i].z = fmaf(zv[i].z, wv[2].z, ACC[i].z);                            \
      ACC[i].w = fmaf(zv[i].z, wv[2].w, ACC[i].w);                            \
      ACC[i].x = fmaf(zv[i].w, wv[3].x, ACC[i].x);                            \
      ACC[i].y = fmaf(zv[i].w, wv[3].y, ACC[i].y);                            \
      ACC[i].z = fmaf(zv[i].w, wv[3].z, ACC[i].z);                            \
      ACC[i].w = fmaf(zv[i].w, wv[3].w, ACC[i].w);                            \
    }                                                                         \
  }

#define RELU4(ACC)                                                            \
  _Pragma("unroll") for (int i = 0; i < 4; ++i) {                             \
    ACC[i].x = fmaxf(ACC[i].x, 0.f);                                          \
    ACC[i].y = fmaxf(ACC[i].y, 0.f);                                          \
    ACC[i].z = fmaxf(ACC[i].z, 0.f);                                          \
    ACC[i].w = fmaxf(ACC[i].w, 0.f);                                          \
  }

  // ---- GEMM1 ----
  float4 acc[4];
  {
    float4 bias = *(float4*)&sb[fc * 4];
#pragma unroll
    for (int i = 0; i < 4; ++i) acc[i] = bias;
  }
  GEMM_HALF(acc, 0)
  __syncthreads();
  for (int i = t; i < 2048; i += 256) sW[i] = W1[2048 + i];
  __syncthreads();
  GEMM_HALF(acc, 8)
  RELU4(acc)
  __syncthreads();

  // write intermediate, stage W2 rows 0..31 + b2
#pragma unroll
  for (int i = 0; i < 4; ++i) *(float4*)&zin[(nr * 4 + i) * 65 + fc * 4] = acc[i];
  for (int i = t; i < 2048; i += 256) sW[i] = W2[i];
  if (t < 64) sb[t] = b2[t];
  __syncthreads();

  // ---- GEMM2 ----
  float4 acc2[4];
  {
    float4 bias = *(float4*)&sb[fc * 4];
#pragma unroll
    for (int i = 0; i < 4; ++i) acc2[i] = bias;
  }
  GEMM_HALF(acc2, 0)
  __syncthreads();
  for (int i = t; i < 2048; i += 256) sW[i] = W2[2048 + i];
  __syncthreads();
  GEMM_HALF(acc2, 8)
  RELU4(acc2)
  __syncthreads();  // zin (intermediate) reads done -> safe to overwrite

  // bf16 store (regular: next layer gathers from L2) + stats partials +
  // stash output tile in zin for pooling
  float4 s4 = {0.f, 0.f, 0.f, 0.f}, q4 = {0.f, 0.f, 0.f, 0.f};
#pragma unroll
  for (int i = 0; i < 4; ++i) {
    int n = nb + nr * 4 + i;
    *(float4*)&zin[(nr * 4 + i) * 65 + fc * 4] = acc2[i];
    if (n < NN) {
      ushort4 ob;
      ob.x = bf16rne(acc2[i].x);
      ob.y = bf16rne(acc2[i].y);
      ob.z = bf16rne(acc2[i].z);
      ob.w = bf16rne(acc2[i].w);
      *(ushort4*)(gbf + (size_t)n * D + fc * 4) = ob;
      s4.x += acc2[i].x; s4.y += acc2[i].y; s4.z += acc2[i].z; s4.w += acc2[i].w;
      q4.x = fmaf(acc2[i].x, acc2[i].x, q4.x);
      q4.y = fmaf(acc2[i].y, acc2[i].y, q4.y);
      q4.z = fmaf(acc2[i].z, acc2[i].z, q4.z);
      q4.w = fmaf(acc2[i].w, acc2[i].w, q4.w);
    }
  }
  __syncthreads();  // zin holds the f32 output tile

  // ---- fused per-graph mean-pool partials (sorted batch segments) ----
  {
    const int nbend = (nb + 64 < NN) ? nb + 64 : NN;
    const int gs = batch_[nb];
    const int ge = batch_[nbend - 1];
    const int c = t & 63, qr = t >> 6;
    for (int g = gs; g <= ge; ++g) {
      int a = gstart_[g];
      int b = gstart_[g + 1];
      a = (a > nb) ? a - nb : 0;
      b = (b < nbend) ? b - nb : nbend - nb;
      float p = 0.f;
      for (int r = a + qr; r < b; r += 4) p += zin[r * 65 + c];
      psum[t] = p;
      __syncthreads();
      if (t < 64) {
        float tot = psum[t] + psum[t + 64] + psum[t + 128] + psum[t + 192];
        unsafeAtomicAdd(&pooledraw[(size_t)g * EMBD + layer * D + t], tot);
      }
      __syncthreads();
    }
  }

  // ---- BN-stats: shfl reduce + LDS combine (zin now dead) ----
#pragma unroll
  for (int m = 16; m <= 32; m <<= 1) {
    s4.x += __shfl_xor(s4.x, m, 64); s4.y += __shfl_xor(s4.y, m, 64);
    s4.z += __shfl_xor(s4.z, m, 64); s4.w += __shfl_xor(s4.w, m, 64);
    q4.x += __shfl_xor(q4.x, m, 64); q4.y += __shfl_xor(q4.y, m, 64);
    q4.z += __shfl_xor(q4.z, m, 64); q4.w += __shfl_xor(q4.w, m, 64);
  }
  int wv_ = t >> 6;
  if ((t & 63) < 16) {
    *(float4*)&zin[wv_ * 64 + fc * 4] = s4;        // sSf = zin[0..255]
    *(float4*)&zin[256 + wv_ * 64 + fc * 4] = q4;  // sQf = zin[256..511]
  }
  __syncthreads();
  if (t < 64) {
    float S = zin[t] + zin[64 + t] + zin[128 + t] + zin[192 + t];
    float Q = zin[256 + t] + zin[320 + t] + zin[384 + t] + zin[448 + t];
    unsafeAtomicAdd(&statsL[t], S);
    unsafeAtomicAdd(&statsL[64 + t], Q);
  }
#undef GEMM_HALF
#undef RELU4
}

// ------- projection head (pool-divide + all 5 layers' BN affine) ----------
__global__ __launch_bounds__(EMBD) void k_proj(const float* __restrict__ pooledraw,
                                               const int* __restrict__ gstart,
                                               const float* __restrict__ stats,
                                               const float* __restrict__ gammas,
                                               const float* __restrict__ betas,
                                               const float* __restrict__ pW1,
                                               const float* __restrict__ pb1,
                                               const float* __restrict__ pW2,
                                               const float* __restrict__ pb2,
                                               float* __restrict__ out) {
  __shared__ float row[EMBD];
  __shared__ float y1[EMBD];
  int g = blockIdx.x, j = threadIdx.x;
  {
    int L = j >> 6, f = j & 63;
    float m = stats[L * 128 + f] * (1.f / NN);
    float v = fmaxf(stats[L * 128 + 64 + f] * (1.f / NN) - m * m, 0.f);
    float sc = gammas[L * D + f] * rsqrtf(v + BN_EPS);
    float sb = betas[L * D + f] - m * sc;
    int cnt = gstart[g + 1] - gstart[g];
    float inv = 1.0f / (float)(cnt > 1 ? cnt : 1);
    row[j] = fmaf(pooledraw[(size_t)g * EMBD + j] * inv, sc, sb);
  }
  __syncthreads();
  float acc = pb1[j];
#pragma unroll 4
  for (int k = 0; k < EMBD; ++k) acc = fmaf(row[k], pW1[(size_t)k * EMBD + j], acc);
  y1[j] = fmaxf(acc, 0.f);
  __syncthreads();
  acc = pb2[j];
#pragma unroll 4
  for (int k = 0; k < EMBD; ++k) acc = fmaf(y1[k], pW2[(size_t)k * EMBD + j], acc);
  out[(size_t)g * EMBD + j] = acc;
}

extern "C" void kernel_launch(void* const* d_in, const int* in_sizes, int n_in,
                              void* d_out, int out_size, void* d_ws, size_t ws_size,
                              hipStream_t stream) {
  const float* x = (const float*)d_in[0];
  const int* ei = (const int*)d_in[1];
  const float* ew = (const float*)d_in[2];
  const int* batch = (const int*)d_in[3];
  const float* W1s = (const float*)d_in[4];
  const float* b1s = (const float*)d_in[5];
  const float* W2s = (const float*)d_in[6];
  const float* b2s = (const float*)d_in[7];
  const float* gammas = (const float*)d_in[8];
  const float* betas = (const float*)d_in[9];
  const float* pW1 = (const float*)d_in[10];
  const float* pb1 = (const float*)d_in[11];
  const float* pW2 = (const float*)d_in[12];
  const float* pb2 = (const float*)d_in[13];
  const int* srcv = ei;
  const int* dstv = ei + NE;

  char* ws = (char*)d_ws;
  float* stats = (float*)ws;                             // NL*128
  float* pooledraw = stats + NL * 128;                   // NG*EMBD (sums)
  int* gstart = (int*)(pooledraw + (size_t)NG * EMBD);   // NG+1
  int* row_ptr = gstart + NG + 1;                        // M2+1 (deg then scan)
  int* cursor = row_ptr + M2 + 1;                        // M2
  long long* epair = (long long*)(cursor + M2);          // NE (8B each)
  int* bsums = (int*)(epair + NE);                       // SCAN2_NB
  unsigned short* hbfA = (unsigned short*)(bsums + SCAN2_NB);  // NN*D bf16
  unsigned short* hbfB = hbfA + (size_t)NN * D;               // NN*D bf16

  // ---- CSR build (src-blocked) + graph bounds + zeroing + x->bf16 ----
  hipMemsetAsync(row_ptr, 0, (M2 + 1) * sizeof(int), stream);
  hipMemsetAsync(stats, 0,
                 (NL * 128 + (size_t)NG * EMBD) * sizeof(float), stream);
  k_hist<<<(NE + 255) / 256, 256, 0, stream>>>(srcv, dstv, row_ptr);
  k_scan1<<<SCAN2_NB, 256, 0, stream>>>(row_ptr, bsums);
  k_scan2<<<1, 1024, 0, stream>>>(bsums);
  k_scan3<<<SCAN2_NB, 256, 0, stream>>>(row_ptr, cursor, bsums);
  k_fill<<<(NE + 255) / 256, 256, 0, stream>>>(srcv, dstv, ew, cursor, epair);
  k_gbound<<<SCAN_NB, 256, 0, stream>>>(batch, gstart);
  k_cvt<<<(NN * 16 + 255) / 256, 256, 0, stream>>>(x, hbfA);

  unsigned short* bfin = hbfA;
  unsigned short* bfout = hbfB;
  for (int L = 0; L < NL; ++L) {
    k_gin<<<GIN_NB, 256, 0, stream>>>(x, bfin, bfout, row_ptr, epair,
                                      batch, gstart, pooledraw, L,
                                      W1s + L * D * D, b1s + L * D,
                                      W2s + L * D * D, b2s + L * D,
                                      stats + (L > 0 ? (L - 1) * 128 : 0),
                                      gammas + (L > 0 ? (L - 1) * D : 0),
                                      betas + (L > 0 ? (L - 1) * D : 0),
                                      L == 0 ? 1 : 0,
                                      stats + L * 128);
    unsigned short* tmpb = bfin;
    bfin = bfout;
    bfout = tmpb;
  }
  k_proj<<<NG, EMBD, 0, stream>>>(pooledraw, gstart, stats, gammas, betas,
                                  pW1, pb1, pW2, pb2, (float*)d_out);
}

// Round 18
// 673.088 us; speedup vs baseline: 1.2150x; 1.1855x over previous
//
#include <hip/hip_runtime.h>

#define NN 100000
#define NE 1600000
#define D 64
#define NL 5
#define NG 1024
#define EMBD 320
#define BN_EPS 1e-5f
#define SCAN_NB ((NN + 255) / 256)   // 391 (gbound)
#define GIN_NB ((NN + 63) / 64)      // 1563
#define SRCB 7                       // src>>14 -> 0..6
#define M2 (NN * SRCB)               // 700000 keys
#define CH 4096                      // edges per chunk
#define NCH ((NE + CH - 1) / CH)     // 391 chunks
#define NBK 196                      // 512-node dst buckets
#define TBL (NBK * NCH)              // 76636
#define SCANT_NB ((TBL + 255) / 256) // 300
#define NKEY 3584                    // 512*7 local keys per bucket

__device__ __forceinline__ unsigned short bf16rne(float f) {
  unsigned u = __float_as_uint(f);
  unsigned r = u + 0x7FFFu + ((u >> 16) & 1u);
  return (unsigned short)(r >> 16);
}
__device__ __forceinline__ float bflo(int v) {
  return __uint_as_float(((unsigned)v) << 16);
}
__device__ __forceinline__ float bfhi(int v) {
  return __uint_as_float(((unsigned)v) & 0xFFFF0000u);
}

// ---------------- fp32 -> bf16 convert (x once per call) ----------------
__global__ __launch_bounds__(256) void k_cvt(const float* __restrict__ in,
                                             unsigned short* __restrict__ outb) {
  int i = blockIdx.x * 256 + threadIdx.x;
  if (i >= NN * 16) return;
  float4 v = ((const float4*)in)[i];
  ushort4 o;
  o.x = bf16rne(v.x); o.y = bf16rne(v.y); o.z = bf16rne(v.z); o.w = bf16rne(v.w);
  ((ushort4*)outb)[i] = o;
}

// ---------------- graph boundaries from sorted batch ----------------
__global__ __launch_bounds__(256) void k_gbound(const int* __restrict__ batch,
                                                int* __restrict__ gstart) {
  int i = blockIdx.x * 256 + threadIdx.x;
  if (i >= NN) return;
  int b = batch[i];
  int bp = (i == 0) ? -1 : batch[i - 1];
  for (int g = bp + 1; g <= b; ++g) gstart[g] = i;
  if (i == NN - 1) {
    for (int g = b + 1; g <= NG; ++g) gstart[g] = NN;
  }
}

// ---- pass A: per-chunk LDS histogram over 196 coarse dst buckets ----
__global__ __launch_bounds__(256) void k_passA(const int* __restrict__ dst,
                                               int* __restrict__ table) {
  __shared__ int lh[NBK];
  for (int i = threadIdx.x; i < NBK; i += 256) lh[i] = 0;
  __syncthreads();
  int base = blockIdx.x * CH;
  int lim = base + CH < NE ? base + CH : NE;
  for (int i = base + threadIdx.x; i < lim; i += 256)
    atomicAdd(&lh[__builtin_nontemporal_load(dst + i) >> 9], 1);
  __syncthreads();
  for (int i = threadIdx.x; i < NBK; i += 256)
    table[i * NCH + blockIdx.x] = lh[i];
}

// ---------------- 3-phase exclusive scan over table (76636) ----------------
__global__ __launch_bounds__(256) void k_scanT1(const int* __restrict__ tab,
                                                int* __restrict__ bsums) {
  __shared__ int sh[256];
  int i = blockIdx.x * 256 + threadIdx.x;
  sh[threadIdx.x] = (i < TBL) ? tab[i] : 0;
  __syncthreads();
  for (int off = 128; off > 0; off >>= 1) {
    if (threadIdx.x < off) sh[threadIdx.x] += sh[threadIdx.x + off];
    __syncthreads();
  }
  if (threadIdx.x == 0) bsums[blockIdx.x] = sh[0];
}

__global__ __launch_bounds__(512) void k_scanT2(int* __restrict__ bsums) {
  __shared__ int sh[512];
  int t = threadIdx.x;
  int v = (t < SCANT_NB) ? bsums[t] : 0;
  sh[t] = v;
  __syncthreads();
  for (int off = 1; off < 512; off <<= 1) {
    int u = (t >= off) ? sh[t - off] : 0;
    __syncthreads();
    sh[t] += u;
    __syncthreads();
  }
  if (t < SCANT_NB) bsums[t] = sh[t] - v;  // exclusive
}

__global__ __launch_bounds__(256) void k_scanT3(int* __restrict__ tab,
                                                const int* __restrict__ bsums) {
  __shared__ int sh[256];
  int t = threadIdx.x;
  int i = blockIdx.x * 256 + t;
  int v = (i < TBL) ? tab[i] : 0;
  sh[t] = v;
  __syncthreads();
  for (int off = 1; off < 256; off <<= 1) {
    int u = (t >= off) ? sh[t - off] : 0;
    __syncthreads();
    sh[t] += u;
    __syncthreads();
  }
  if (i < TBL) tab[i] = sh[t] - v + bsums[blockIdx.x];
}

// ---- pass B: scatter edges to bucket regions (LDS cursors, no g-atomics) --
// tmp pack: lo = src(17b) | dlocal(9b)<<17 ; hi = w bits
__global__ __launch_bounds__(256) void k_passB(const int* __restrict__ src,
                                               const int* __restrict__ dst,
                                               const float* __restrict__ w,
                                               const int* __restrict__ table,
                                               long long* __restrict__ tmp) {
  __shared__ int lbase[NBK];
  __shared__ int lcur[NBK];
  for (int i = threadIdx.x; i < NBK; i += 256) {
    lbase[i] = table[i * NCH + blockIdx.x];
    lcur[i] = 0;
  }
  __syncthreads();
  int base = blockIdx.x * CH;
  int lim = base + CH < NE ? base + CH : NE;
  for (int i = base + threadIdx.x; i < lim; i += 256) {
    int s = __builtin_nontemporal_load(src + i);
    int d = __builtin_nontemporal_load(dst + i);
    float we = __builtin_nontemporal_load(w + i);
    int b = d >> 9;
    int slot = lbase[b] + atomicAdd(&lcur[b], 1);
    long long p = (long long)(unsigned)(s | ((d & 511) << 17)) |
                  ((long long)(unsigned)__float_as_int(we) << 32);
    tmp[slot] = p;
  }
}

// ---- pass C: bucket-local counting sort -> final epair + row_ptr ----
__global__ __launch_bounds__(512) void k_passC(const long long* __restrict__ tmp,
                                               const int* __restrict__ table,
                                               int* __restrict__ row_ptr,
                                               long long* __restrict__ epair) {
  __shared__ int kh[NKEY];
  __shared__ int aux[512];
  const int t = threadIdx.x;
  const int b = blockIdx.x;
  const int bb = table[b * NCH];
  const int be = (b == NBK - 1) ? NE : table[(b + 1) * NCH];
  for (int i = t; i < NKEY; i += 512) kh[i] = 0;
  __syncthreads();
  // histogram over local keys
  for (int i = bb + t; i < be; i += 512) {
    long long e = tmp[i];
    int lo = (int)e;
    int ln = (lo >> 17) & 511;
    int s = lo & 0x1FFFF;
    atomicAdd(&kh[ln * 7 + (s >> 14)], 1);
  }
  __syncthreads();
  // exclusive scan of kh (each thread owns 7 consecutive keys)
  int loc[7];
  int ssum = 0;
#pragma unroll
  for (int j = 0; j < 7; ++j) {
    loc[j] = ssum;
    ssum += kh[t * 7 + j];
  }
  aux[t] = ssum;
  __syncthreads();
  for (int off = 1; off < 512; off <<= 1) {
    int u = (t >= off) ? aux[t - off] : 0;
    __syncthreads();
    aux[t] += u;
    __syncthreads();
  }
  int excl = aux[t] - ssum;
#pragma unroll
  for (int j = 0; j < 7; ++j) kh[t * 7 + j] = excl + loc[j];
  __syncthreads();
  // write row_ptr (global key = (b*512+ln)*7 + sb), then place edges
  const int nodebase = b * 512;
  for (int i = t; i < NKEY; i += 512) {
    int node = nodebase + i / 7;
    if (node < NN) row_ptr[(size_t)node * 7 + (i % 7)] = bb + kh[i];
  }
  if (b == NBK - 1 && t == 0) row_ptr[M2] = NE;
  __syncthreads();
  for (int i = bb + t; i < be; i += 512) {
    long long e = tmp[i];
    int lo = (int)e;
    int ln = (lo >> 17) & 511;
    int s = lo & 0x1FFFF;
    int slot = bb + atomicAdd(&kh[ln * 7 + (s >> 14)], 1);
    epair[slot] = (long long)(unsigned)s |
                  (e & 0xFFFFFFFF00000000ll);
  }
}

// ---- fused gather(bf16) + deferred-BN + GIN MLP + BN-stats + pooling -----
#define ACC8(CA, CB, WE)                                                      \
  a0.x = fmaf(bflo(CA.x), WE, a0.x); a0.y = fmaf(bfhi(CA.x), WE, a0.y);       \
  a0.z = fmaf(bflo(CA.y), WE, a0.z); a0.w = fmaf(bfhi(CA.y), WE, a0.w);       \
  a1.x = fmaf(bflo(CA.z), WE, a1.x); a1.y = fmaf(bfhi(CA.z), WE, a1.y);       \
  a1.z = fmaf(bflo(CA.w), WE, a1.z); a1.w = fmaf(bfhi(CA.w), WE, a1.w);       \
  a2.x = fmaf(bflo(CB.x), WE, a2.x); a2.y = fmaf(bfhi(CB.x), WE, a2.y);       \
  a2.z = fmaf(bflo(CB.y), WE, a2.z); a2.w = fmaf(bfhi(CB.y), WE, a2.w);       \
  a3.x = fmaf(bflo(CB.z), WE, a3.x); a3.y = fmaf(bfhi(CB.z), WE, a3.y);       \
  a3.z = fmaf(bflo(CB.w), WE, a3.z); a3.w = fmaf(bfhi(CB.w), WE, a3.w);

__global__ __launch_bounds__(256, 6) void k_gin(const float* __restrict__ x0,
                                                const unsigned short* __restrict__ hbf,
                                                unsigned short* __restrict__ gbf,
                                                const int* __restrict__ row_ptr,
                                                const long long* __restrict__ epair,
                                                const int* __restrict__ batch_,
                                                const int* __restrict__ gstart_,
                                                float* __restrict__ pooledraw,
                                                int layer,
                                                const float* __restrict__ W1,
                                                const float* __restrict__ b1,
                                                const float* __restrict__ W2,
                                                const float* __restrict__ b2,
                                                const float* __restrict__ statsP,
                                                const float* __restrict__ gammaP,
                                                const float* __restrict__ betaP,
                                                int first,
                                                float* __restrict__ statsL) {
  __shared__ float zin[64 * 65];   // z-tile, then output tile, then stats scratch
  __shared__ float sW[32 * 64];    // half of one weight matrix
  __shared__ float sb[64];
  __shared__ float wsumS[64];
  __shared__ float scA[64], sbA[64];
  __shared__ float psum[256];
  const int t = threadIdx.x;
  const int nb = blockIdx.x * 64;
  const int nr = t >> 4, fc = t & 15;

  // stage W1 rows 0..31, b1; prev-layer affine coeffs
  for (int i = t; i < 2048; i += 256) sW[i] = W1[i];
  if (t < 64) {
    sb[t] = b1[t];
    if (!first) {
      float m = statsP[t] * (1.f / NN);
      float v = fmaxf(statsP[64 + t] * (1.f / NN) - m * m, 0.f);
      float sc = gammaP[t] * rsqrtf(v + BN_EPS);
      scA[t] = sc;
      sbA[t] = betaP[t] - m * sc;
    }
  }

  // staging: bf16 gather (unroll 2, nt epair) + own term -> zin
  {
    const int nl = t >> 2;        // 0..63 local node
    const int q = t & 3;          // quarter of the row (16 cols)
    const int n = nb + nl;
    float4 a0 = {0.f, 0.f, 0.f, 0.f}, a1 = a0, a2 = a0, a3 = a0;
    float wsum = 0.f;
    if (n < NN) {
      const int beg = row_ptr[n * SRCB], end = row_ptr[n * SRCB + SRCB];
      int i = beg;
      for (; i + 2 <= end; i += 2) {
        long long e0 = __builtin_nontemporal_load(epair + i);
        long long e1 = __builtin_nontemporal_load(epair + i + 1);
        int s0 = (int)(e0 & 0xFFFFFFFFll);
        float w0 = __int_as_float((int)(e0 >> 32));
        int s1 = (int)(e1 & 0xFFFFFFFFll);
        float w1 = __int_as_float((int)(e1 >> 32));
        const int4* p0 = (const int4*)(hbf + (size_t)s0 * D);
        const int4* p1 = (const int4*)(hbf + (size_t)s1 * D);
        int4 r0a = p0[2 * q], r0b = p0[2 * q + 1];
        int4 r1a = p1[2 * q], r1b = p1[2 * q + 1];
        ACC8(r0a, r0b, w0)
        wsum += w0;
        ACC8(r1a, r1b, w1)
        wsum += w1;
      }
      for (; i < end; ++i) {
        long long e0 = __builtin_nontemporal_load(epair + i);
        int s0 = (int)(e0 & 0xFFFFFFFFll);
        float w0 = __int_as_float((int)(e0 >> 32));
        const int4* p0 = (const int4*)(hbf + (size_t)s0 * D);
        int4 r0a = p0[2 * q], r0b = p0[2 * q + 1];
        ACC8(r0a, r0b, w0)
        wsum += w0;
      }
      // own term: fp32 x for layer 0 (single pass), bf16 after
      if (first) {
        const float4* own = (const float4*)(x0 + (size_t)n * D) + q * 4;
        float4 o0 = own[0], o1 = own[1], o2 = own[2], o3 = own[3];
        a0.x += o0.x; a0.y += o0.y; a0.z += o0.z; a0.w += o0.w;
        a1.x += o1.x; a1.y += o1.y; a1.z += o1.z; a1.w += o1.w;
        a2.x += o2.x; a2.y += o2.y; a2.z += o2.z; a2.w += o2.w;
        a3.x += o3.x; a3.y += o3.y; a3.z += o3.z; a3.w += o3.w;
      } else {
        const int4* hp = (const int4*)(hbf + (size_t)n * D);
        int4 c0 = hp[2 * q], c1 = hp[2 * q + 1];
        a0.x += bflo(c0.x); a0.y += bfhi(c0.x);
        a0.z += bflo(c0.y); a0.w += bfhi(c0.y);
        a1.x += bflo(c0.z); a1.y += bfhi(c0.z);
        a1.z += bflo(c0.w); a1.w += bfhi(c0.w);
        a2.x += bflo(c1.x); a2.y += bfhi(c1.x);
        a2.z += bflo(c1.y); a2.w += bfhi(c1.y);
        a3.x += bflo(c1.z); a3.y += bfhi(c1.z);
        a3.z += bflo(c1.w); a3.w += bfhi(c1.w);
      }
    }
    float* zr = &zin[nl * 65 + q * 16];
    *(float4*)(zr + 0) = a0;
    *(float4*)(zr + 4) = a1;
    *(float4*)(zr + 8) = a2;
    *(float4*)(zr + 12) = a3;
    if (q == 0) wsumS[nl] = wsum;
  }
  __syncthreads();

  // deferred-BN affine pass over the z-tile
  if (!first) {
#pragma unroll
    for (int pass = 0; pass < 4; ++pass) {
      int idx = pass * 1024 + t * 4;
      int r = idx >> 6, c = idx & 63;
      float wp1 = 1.f + wsumS[r];
      float4 z = *(float4*)&zin[r * 65 + c];
      z.x = fmaf(z.x, scA[c + 0], sbA[c + 0] * wp1);
      z.y = fmaf(z.y, scA[c + 1], sbA[c + 1] * wp1);
      z.z = fmaf(z.z, scA[c + 2], sbA[c + 2] * wp1);
      z.w = fmaf(z.w, scA[c + 3], sbA[c + 3] * wp1);
      *(float4*)&zin[r * 65 + c] = z;
    }
    __syncthreads();
  }

#define GEMM_HALF(ACC, KBASE)                                                 \
  _Pragma("unroll 2") for (int kc = 0; kc < 8; ++kc) {                        \
    float4 zv[4], wv[4];                                                      \
    _Pragma("unroll") for (int i = 0; i < 4; ++i)                             \
        zv[i] = *(float4*)&zin[(nr * 4 + i) * 65 + ((KBASE) + kc) * 4];       \
    _Pragma("unroll") for (int kk = 0; kk < 4; ++kk)                          \
        wv[kk] = *(float4*)&sW[(kc * 4 + kk) * 64 + fc * 4];                  \
    _Pragma("unroll") for (int i = 0; i < 4; ++i) {                           \
      ACC[i].x = fmaf(zv[i].x, wv[0].x, ACC[i].x);                            \
      ACC[i].y = fmaf(zv[i].x, wv[0].y, ACC[i].y);                            \
      ACC[i].z = fmaf(zv[i].x, wv[0].z, ACC[i].z);                            \
      ACC[i].w = fmaf(zv[i].x, wv[0].w, ACC[i].w);                            \
      ACC[i].x = fmaf(zv[i].y, wv[1].x, ACC[i].x);                            \
      ACC[i].y = fmaf(zv[i].y, wv[1].y, ACC[i].y);                            \
      ACC[i].z = fmaf(zv[i].y, wv[1].z, ACC[i].z);                            \
      ACC[i].w = fmaf(zv[i].y, wv[1].w, ACC[i].w);                            \
      ACC[i].x = fmaf(zv[i].z, wv[2].x, ACC[i].x);                            \
      ACC[i].y = fmaf(zv[i].z, wv[2].y, ACC[i].y);                            \
      ACC[i].z = fmaf(zv[i].z, wv[2].z, ACC[i].z);                            \
      ACC[i].w = fmaf(zv[i].z, wv[2].w, ACC[i].w);                            \
      ACC[i].x = fmaf(zv[i].w, wv[3].x, ACC[i].x);                            \
      ACC[i].y = fmaf(zv[i].w, wv[3].y, ACC[i].y);                            \
      ACC[i].z = fmaf(zv[i].w, wv[3].z, ACC[i].z);                            \
      ACC[i].w = fmaf(zv[i].w, wv[3].w, ACC[i].w);                            \
    }                                                                         \
  }

#define RELU4(ACC)                                                            \
  _Pragma("unroll") for (int i = 0; i < 4; ++i) {                             \
    ACC[i].x = fmaxf(ACC[i].x, 0.f);                                          \
    ACC[i].y = fmaxf(ACC[i].y, 0.f);                                          \
    ACC[i].z = fmaxf(ACC[i].z, 0.f);                                          \
    ACC[i].w = fmaxf(ACC[i].w, 0.f);                                          \
  }

  // ---- GEMM1 ----
  float4 acc[4];
  {
    float4 bias = *(float4*)&sb[fc * 4];
#pragma unroll
    for (int i = 0; i < 4; ++i) acc[i] = bias;
  }
  GEMM_HALF(acc, 0)
  __syncthreads();
  for (int i = t; i < 2048; i += 256) sW[i] = W1[2048 + i];
  __syncthreads();
  GEMM_HALF(acc, 8)
  RELU4(acc)
  __syncthreads();

  // write intermediate, stage W2 rows 0..31 + b2
#pragma unroll
  for (int i = 0; i < 4; ++i) *(float4*)&zin[(nr * 4 + i) * 65 + fc * 4] = acc[i];
  for (int i = t; i < 2048; i += 256) sW[i] = W2[i];
  if (t < 64) sb[t] = b2[t];
  __syncthreads();

  // ---- GEMM2 ----
  float4 acc2[4];
  {
    float4 bias = *(float4*)&sb[fc * 4];
#pragma unroll
    for (int i = 0; i < 4; ++i) acc2[i] = bias;
  }
  GEMM_HALF(acc2, 0)
  __syncthreads();
  for (int i = t; i < 2048; i += 256) sW[i] = W2[2048 + i];
  __syncthreads();
  GEMM_HALF(acc2, 8)
  RELU4(acc2)
  __syncthreads();  // zin (intermediate) reads done -> safe to overwrite

  // bf16 store + stats partials + stash output tile in zin for pooling
  float4 s4 = {0.f, 0.f, 0.f, 0.f}, q4 = {0.f, 0.f, 0.f, 0.f};
#pragma unroll
  for (int i = 0; i < 4; ++i) {
    int n = nb + nr * 4 + i;
    *(float4*)&zin[(nr * 4 + i) * 65 + fc * 4] = acc2[i];
    if (n < NN) {
      ushort4 ob;
      ob.x = bf16rne(acc2[i].x);
      ob.y = bf16rne(acc2[i].y);
      ob.z = bf16rne(acc2[i].z);
      ob.w = bf16rne(acc2[i].w);
      *(ushort4*)(gbf + (size_t)n * D + fc * 4) = ob;
      s4.x += acc2[i].x; s4.y += acc2[i].y; s4.z += acc2[i].z; s4.w += acc2[i].w;
      q4.x = fmaf(acc2[i].x, acc2[i].x, q4.x);
      q4.y = fmaf(acc2[i].y, acc2[i].y, q4.y);
      q4.z = fmaf(acc2[i].z, acc2[i].z, q4.z);
      q4.w = fmaf(acc2[i].w, acc2[i].w, q4.w);
    }
  }
  __syncthreads();  // zin holds the f32 output tile

  // ---- fused per-graph mean-pool partials (sorted batch segments) ----
  {
    const int nbend = (nb + 64 < NN) ? nb + 64 : NN;
    const int gs = batch_[nb];
    const int ge = batch_[nbend - 1];
    const int c = t & 63, qr = t >> 6;
    for (int g = gs; g <= ge; ++g) {
      int a = gstart_[g];
      int b = gstart_[g + 1];
      a = (a > nb) ? a - nb : 0;
      b = (b < nbend) ? b - nb : nbend - nb;
      float p = 0.f;
      for (int r = a + qr; r < b; r += 4) p += zin[r * 65 + c];
      psum[t] = p;
      __syncthreads();
      if (t < 64) {
        float tot = psum[t] + psum[t + 64] + psum[t + 128] + psum[t + 192];
        unsafeAtomicAdd(&pooledraw[(size_t)g * EMBD + layer * D + t], tot);
      }
      __syncthreads();
    }
  }

  // ---- BN-stats: shfl reduce + LDS combine (zin now dead) ----
#pragma unroll
  for (int m = 16; m <= 32; m <<= 1) {
    s4.x += __shfl_xor(s4.x, m, 64); s4.y += __shfl_xor(s4.y, m, 64);
    s4.z += __shfl_xor(s4.z, m, 64); s4.w += __shfl_xor(s4.w, m, 64);
    q4.x += __shfl_xor(q4.x, m, 64); q4.y += __shfl_xor(q4.y, m, 64);
    q4.z += __shfl_xor(q4.z, m, 64); q4.w += __shfl_xor(q4.w, m, 64);
  }
  int wv_ = t >> 6;
  if ((t & 63) < 16) {
    *(float4*)&zin[wv_ * 64 + fc * 4] = s4;        // sSf = zin[0..255]
    *(float4*)&zin[256 + wv_ * 64 + fc * 4] = q4;  // sQf = zin[256..511]
  }
  __syncthreads();
  if (t < 64) {
    float S = zin[t] + zin[64 + t] + zin[128 + t] + zin[192 + t];
    float Q = zin[256 + t] + zin[320 + t] + zin[384 + t] + zin[448 + t];
    unsafeAtomicAdd(&statsL[t], S);
    unsafeAtomicAdd(&statsL[64 + t], Q);
  }
#undef GEMM_HALF
#undef RELU4
}

// ------- projection head (pool-divide + all 5 layers' BN affine) ----------
__global__ __launch_bounds__(EMBD) void k_proj(const float* __restrict__ pooledraw,
                                               const int* __restrict__ gstart,
                                               const float* __restrict__ stats,
                                               const float* __restrict__ gammas,
                                               const float* __restrict__ betas,
                                               const float* __restrict__ pW1,
                                               const float* __restrict__ pb1,
                                               const float* __restrict__ pW2,
                                               const float* __restrict__ pb2,
                                               float* __restrict__ out) {
  __shared__ float row[EMBD];
  __shared__ float y1[EMBD];
  int g = blockIdx.x, j = threadIdx.x;
  {
    int L = j >> 6, f = j & 63;
    float m = stats[L * 128 + f] * (1.f / NN);
    float v = fmaxf(stats[L * 128 + 64 + f] * (1.f / NN) - m * m, 0.f);
    float sc = gammas[L * D + f] * rsqrtf(v + BN_EPS);
    float sb = betas[L * D + f] - m * sc;
    int cnt = gstart[g + 1] - gstart[g];
    float inv = 1.0f / (float)(cnt > 1 ? cnt : 1);
    row[j] = fmaf(pooledraw[(size_t)g * EMBD + j] * inv, sc, sb);
  }
  __syncthreads();
  float acc = pb1[j];
#pragma unroll 4
  for (int k = 0; k < EMBD; ++k) acc = fmaf(row[k], pW1[(size_t)k * EMBD + j], acc);
  y1[j] = fmaxf(acc, 0.f);
  __syncthreads();
  acc = pb2[j];
#pragma unroll 4
  for (int k = 0; k < EMBD; ++k) acc = fmaf(y1[k], pW2[(size_t)k * EMBD + j], acc);
  out[(size_t)g * EMBD + j] = acc;
}

extern "C" void kernel_launch(void* const* d_in, const int* in_sizes, int n_in,
                              void* d_out, int out_size, void* d_ws, size_t ws_size,
                              hipStream_t stream) {
  const float* x = (const float*)d_in[0];
  const int* ei = (const int*)d_in[1];
  const float* ew = (const float*)d_in[2];
  const int* batch = (const int*)d_in[3];
  const float* W1s = (const float*)d_in[4];
  const float* b1s = (const float*)d_in[5];
  const float* W2s = (const float*)d_in[6];
  const float* b2s = (const float*)d_in[7];
  const float* gammas = (const float*)d_in[8];
  const float* betas = (const float*)d_in[9];
  const float* pW1 = (const float*)d_in[10];
  const float* pb1 = (const float*)d_in[11];
  const float* pW2 = (const float*)d_in[12];
  const float* pb2 = (const float*)d_in[13];
  const int* srcv = ei;
  const int* dstv = ei + NE;

  char* ws = (char*)d_ws;
  float* stats = (float*)ws;                             // NL*128
  float* pooledraw = stats + NL * 128;                   // NG*EMBD (sums)
  int* gstart = (int*)(pooledraw + (size_t)NG * EMBD);   // NG+1
  int* row_ptr = gstart + NG + 1;                        // M2+1
  int* table = row_ptr + M2 + 1;                         // TBL
  int* bsums = table + TBL;                              // SCANT_NB
  long long* tmp = (long long*)(bsums + SCANT_NB + 1);   // NE (8B)
  long long* epair = tmp + NE;                           // NE (8B)
  unsigned short* hbfA = (unsigned short*)(epair + NE);  // NN*D bf16
  unsigned short* hbfB = hbfA + (size_t)NN * D;          // NN*D bf16

  // ---- CSR build (two-level counting sort) + graph bounds + zeroing ----
  hipMemsetAsync(stats, 0,
                 (NL * 128 + (size_t)NG * EMBD) * sizeof(float), stream);
  k_passA<<<NCH, 256, 0, stream>>>(dstv, table);
  k_scanT1<<<SCANT_NB, 256, 0, stream>>>(table, bsums);
  k_scanT2<<<1, 512, 0, stream>>>(bsums);
  k_scanT3<<<SCANT_NB, 256, 0, stream>>>(table, bsums);
  k_passB<<<NCH, 256, 0, stream>>>(srcv, dstv, ew, table, tmp);
  k_passC<<<NBK, 512, 0, stream>>>(tmp, table, row_ptr, epair);
  k_gbound<<<SCAN_NB, 256, 0, stream>>>(batch, gstart);
  k_cvt<<<(NN * 16 + 255) / 256, 256, 0, stream>>>(x, hbfA);

  unsigned short* bfin = hbfA;
  unsigned short* bfout = hbfB;
  for (int L = 0; L < NL; ++L) {
    k_gin<<<GIN_NB, 256, 0, stream>>>(x, bfin, bfout, row_ptr, epair,
                                      batch, gstart, pooledraw, L,
                                      W1s + L * D * D, b1s + L * D,
                                      W2s + L * D * D, b2s + L * D,
                                      stats + (L > 0 ? (L - 1) * 128 : 0),
                                      gammas + (L > 0 ? (L - 1) * D : 0),
                                      betas + (L > 0 ? (L - 1) * D : 0),
                                      L == 0 ? 1 : 0,
                                      stats + L * 128);
    unsigned short* tmpb = bfin;
    bfin = bfout;
    bfout = tmpb;
  }
  k_proj<<<NG, EMBD, 0, stream>>>(pooledraw, gstart, stats, gammas, betas,
                                  pW1, pb1, pW2, pb2, (float*)d_out);
}

// Round 19
// 667.026 us; speedup vs baseline: 1.2260x; 1.0091x over previous
//
#include <hip/hip_runtime.h>

#define NN 100000
#define NE 1600000
#define D 64
#define NL 5
#define NG 1024
#define EMBD 320
#define BN_EPS 1e-5f
#define SCAN_NB ((NN + 255) / 256)   // 391 (gbound)
#define GIN_NB ((NN + 63) / 64)      // 1563
#define SRCB 7                       // src>>14 -> 0..6
#define M2 (NN * SRCB)               // 700000 keys
#define CH 4096                      // edges per chunk
#define NCH ((NE + CH - 1) / CH)     // 391 chunks
#define NBK 196                      // 512-node dst buckets
#define TBL (NBK * NCH)              // 76636
#define SCANT_NB ((TBL + 255) / 256) // 300
#define NKEY 3584                    // 512*7 local keys per bucket

__device__ __forceinline__ unsigned short bf16rne(float f) {
  unsigned u = __float_as_uint(f);
  unsigned r = u + 0x7FFFu + ((u >> 16) & 1u);
  return (unsigned short)(r >> 16);
}
__device__ __forceinline__ float bflo(int v) {
  return __uint_as_float(((unsigned)v) << 16);
}
__device__ __forceinline__ float bfhi(int v) {
  return __uint_as_float(((unsigned)v) & 0xFFFF0000u);
}

// ---------------- fp32 -> bf16 convert (x once per call) ----------------
__global__ __launch_bounds__(256) void k_cvt(const float* __restrict__ in,
                                             unsigned short* __restrict__ outb) {
  int i = blockIdx.x * 256 + threadIdx.x;
  if (i >= NN * 16) return;
  float4 v = ((const float4*)in)[i];
  ushort4 o;
  o.x = bf16rne(v.x); o.y = bf16rne(v.y); o.z = bf16rne(v.z); o.w = bf16rne(v.w);
  ((ushort4*)outb)[i] = o;
}

// ---------------- graph boundaries from sorted batch ----------------
__global__ __launch_bounds__(256) void k_gbound(const int* __restrict__ batch,
                                                int* __restrict__ gstart) {
  int i = blockIdx.x * 256 + threadIdx.x;
  if (i >= NN) return;
  int b = batch[i];
  int bp = (i == 0) ? -1 : batch[i - 1];
  for (int g = bp + 1; g <= b; ++g) gstart[g] = i;
  if (i == NN - 1) {
    for (int g = b + 1; g <= NG; ++g) gstart[g] = NN;
  }
}

// ---- pass A: per-chunk LDS histogram over 196 coarse dst buckets ----
__global__ __launch_bounds__(256) void k_passA(const int* __restrict__ dst,
                                               int* __restrict__ table) {
  __shared__ int lh[NBK];
  for (int i = threadIdx.x; i < NBK; i += 256) lh[i] = 0;
  __syncthreads();
  int base = blockIdx.x * CH;
  int lim = base + CH < NE ? base + CH : NE;
  for (int i = base + threadIdx.x; i < lim; i += 256)
    atomicAdd(&lh[__builtin_nontemporal_load(dst + i) >> 9], 1);
  __syncthreads();
  for (int i = threadIdx.x; i < NBK; i += 256)
    table[i * NCH + blockIdx.x] = lh[i];
}

// ---------------- 3-phase exclusive scan over table (76636) ----------------
__global__ __launch_bounds__(256) void k_scanT1(const int* __restrict__ tab,
                                                int* __restrict__ bsums) {
  __shared__ int sh[256];
  int i = blockIdx.x * 256 + threadIdx.x;
  sh[threadIdx.x] = (i < TBL) ? tab[i] : 0;
  __syncthreads();
  for (int off = 128; off > 0; off >>= 1) {
    if (threadIdx.x < off) sh[threadIdx.x] += sh[threadIdx.x + off];
    __syncthreads();
  }
  if (threadIdx.x == 0) bsums[blockIdx.x] = sh[0];
}

__global__ __launch_bounds__(512) void k_scanT2(int* __restrict__ bsums) {
  __shared__ int sh[512];
  int t = threadIdx.x;
  int v = (t < SCANT_NB) ? bsums[t] : 0;
  sh[t] = v;
  __syncthreads();
  for (int off = 1; off < 512; off <<= 1) {
    int u = (t >= off) ? sh[t - off] : 0;
    __syncthreads();
    sh[t] += u;
    __syncthreads();
  }
  if (t < SCANT_NB) bsums[t] = sh[t] - v;  // exclusive
}

__global__ __launch_bounds__(256) void k_scanT3(int* __restrict__ tab,
                                                const int* __restrict__ bsums) {
  __shared__ int sh[256];
  int t = threadIdx.x;
  int i = blockIdx.x * 256 + t;
  int v = (i < TBL) ? tab[i] : 0;
  sh[t] = v;
  __syncthreads();
  for (int off = 1; off < 256; off <<= 1) {
    int u = (t >= off) ? sh[t - off] : 0;
    __syncthreads();
    sh[t] += u;
    __syncthreads();
  }
  if (i < TBL) tab[i] = sh[t] - v + bsums[blockIdx.x];
}

// ---- pass B: scatter edges to bucket regions (LDS cursors, no g-atomics) --
// tmp pack: lo = src(17b) | dlocal(9b)<<17 ; hi = w bits
__global__ __launch_bounds__(256) void k_passB(const int* __restrict__ src,
                                               const int* __restrict__ dst,
                                               const float* __restrict__ w,
                                               const int* __restrict__ table,
                                               long long* __restrict__ tmp) {
  __shared__ int lbase[NBK];
  __shared__ int lcur[NBK];
  for (int i = threadIdx.x; i < NBK; i += 256) {
    lbase[i] = table[i * NCH + blockIdx.x];
    lcur[i] = 0;
  }
  __syncthreads();
  int base = blockIdx.x * CH;
  int lim = base + CH < NE ? base + CH : NE;
  for (int i = base + threadIdx.x; i < lim; i += 256) {
    int s = __builtin_nontemporal_load(src + i);
    int d = __builtin_nontemporal_load(dst + i);
    float we = __builtin_nontemporal_load(w + i);
    int b = d >> 9;
    int slot = lbase[b] + atomicAdd(&lcur[b], 1);
    long long p = (long long)(unsigned)(s | ((d & 511) << 17)) |
                  ((long long)(unsigned)__float_as_int(we) << 32);
    tmp[slot] = p;
  }
}

// ---- pass C: bucket-local counting sort -> final epair + row_ptr ----
__global__ __launch_bounds__(512) void k_passC(const long long* __restrict__ tmp,
                                               const int* __restrict__ table,
                                               int* __restrict__ row_ptr,
                                               long long* __restrict__ epair) {
  __shared__ int kh[NKEY];
  __shared__ int aux[512];
  const int t = threadIdx.x;
  const int b = blockIdx.x;
  const int bb = table[b * NCH];
  const int be = (b == NBK - 1) ? NE : table[(b + 1) * NCH];
  for (int i = t; i < NKEY; i += 512) kh[i] = 0;
  __syncthreads();
  // histogram over local keys
  for (int i = bb + t; i < be; i += 512) {
    long long e = tmp[i];
    int lo = (int)e;
    int ln = (lo >> 17) & 511;
    int s = lo & 0x1FFFF;
    atomicAdd(&kh[ln * 7 + (s >> 14)], 1);
  }
  __syncthreads();
  // exclusive scan of kh (each thread owns 7 consecutive keys)
  int loc[7];
  int ssum = 0;
#pragma unroll
  for (int j = 0; j < 7; ++j) {
    loc[j] = ssum;
    ssum += kh[t * 7 + j];
  }
  aux[t] = ssum;
  __syncthreads();
  for (int off = 1; off < 512; off <<= 1) {
    int u = (t >= off) ? aux[t - off] : 0;
    __syncthreads();
    aux[t] += u;
    __syncthreads();
  }
  int excl = aux[t] - ssum;
#pragma unroll
  for (int j = 0; j < 7; ++j) kh[t * 7 + j] = excl + loc[j];
  __syncthreads();
  // write row_ptr (global key = (b*512+ln)*7 + sb), then place edges
  const int nodebase = b * 512;
  for (int i = t; i < NKEY; i += 512) {
    int node = nodebase + i / 7;
    if (node < NN) row_ptr[(size_t)node * 7 + (i % 7)] = bb + kh[i];
  }
  if (b == NBK - 1 && t == 0) row_ptr[M2] = NE;
  __syncthreads();
  for (int i = bb + t; i < be; i += 512) {
    long long e = tmp[i];
    int lo = (int)e;
    int ln = (lo >> 17) & 511;
    int s = lo & 0x1FFFF;
    int slot = bb + atomicAdd(&kh[ln * 7 + (s >> 14)], 1);
    epair[slot] = (long long)(unsigned)s |
                  (e & 0xFFFFFFFF00000000ll);
  }
}

// ---- fused gather(bf16) + deferred-BN + GIN MLP + BN-stats + pooling -----
#define ACC8(CA, CB, WE)                                                      \
  a0.x = fmaf(bflo(CA.x), WE, a0.x); a0.y = fmaf(bfhi(CA.x), WE, a0.y);       \
  a0.z = fmaf(bflo(CA.y), WE, a0.z); a0.w = fmaf(bfhi(CA.y), WE, a0.w);       \
  a1.x = fmaf(bflo(CA.z), WE, a1.x); a1.y = fmaf(bfhi(CA.z), WE, a1.y);       \
  a1.z = fmaf(bflo(CA.w), WE, a1.z); a1.w = fmaf(bfhi(CA.w), WE, a1.w);       \
  a2.x = fmaf(bflo(CB.x), WE, a2.x); a2.y = fmaf(bfhi(CB.x), WE, a2.y);       \
  a2.z = fmaf(bflo(CB.y), WE, a2.z); a2.w = fmaf(bfhi(CB.y), WE, a2.w);       \
  a3.x = fmaf(bflo(CB.z), WE, a3.x); a3.y = fmaf(bfhi(CB.z), WE, a3.y);       \
  a3.z = fmaf(bflo(CB.w), WE, a3.z); a3.w = fmaf(bfhi(CB.w), WE, a3.w);

__global__ __launch_bounds__(256, 6) void k_gin(const float* __restrict__ x0,
                                                const unsigned short* __restrict__ hbf,
                                                unsigned short* __restrict__ gbf,
                                                const int* __restrict__ row_ptr,
                                                const long long* __restrict__ epair,
                                                const int* __restrict__ batch_,
                                                const int* __restrict__ gstart_,
                                                float* __restrict__ pooledraw,
                                                int layer,
                                                const float* __restrict__ W1,
                                                const float* __restrict__ b1,
                                                const float* __restrict__ W2,
                                                const float* __restrict__ b2,
                                                const float* __restrict__ statsP,
                                                const float* __restrict__ gammaP,
                                                const float* __restrict__ betaP,
                                                int first,
                                                float* __restrict__ statsL) {
  __shared__ float zin[64 * 65];   // z-tile, then output tile, then stats scratch
  __shared__ float sW[32 * 64];    // half of one weight matrix
  __shared__ float sb[64];
  __shared__ float wsumS[64];
  __shared__ float scA[64], sbA[64];
  __shared__ float psum[256];
  const int t = threadIdx.x;
  const int nb = blockIdx.x * 64;
  const int nr = t >> 4, fc = t & 15;

  // stage W1 rows 0..31, b1; prev-layer affine coeffs
  for (int i = t; i < 2048; i += 256) sW[i] = W1[i];
  if (t < 64) {
    sb[t] = b1[t];
    if (!first) {
      float m = statsP[t] * (1.f / NN);
      float v = fmaxf(statsP[64 + t] * (1.f / NN) - m * m, 0.f);
      float sc = gammaP[t] * rsqrtf(v + BN_EPS);
      scA[t] = sc;
      sbA[t] = betaP[t] - m * sc;
    }
  }

  // staging: bf16 gather (unroll 2, nt epair) + own term -> zin
  {
    const int nl = t >> 2;        // 0..63 local node
    const int q = t & 3;          // quarter of the row (16 cols)
    const int n = nb + nl;
    float4 a0 = {0.f, 0.f, 0.f, 0.f}, a1 = a0, a2 = a0, a3 = a0;
    float wsum = 0.f;
    if (n < NN) {
      const int beg = row_ptr[n * SRCB], end = row_ptr[n * SRCB + SRCB];
      int i = beg;
      for (; i + 2 <= end; i += 2) {
        long long e0 = __builtin_nontemporal_load(epair + i);
        long long e1 = __builtin_nontemporal_load(epair + i + 1);
        int s0 = (int)(e0 & 0xFFFFFFFFll);
        float w0 = __int_as_float((int)(e0 >> 32));
        int s1 = (int)(e1 & 0xFFFFFFFFll);
        float w1 = __int_as_float((int)(e1 >> 32));
        const int4* p0 = (const int4*)(hbf + (size_t)s0 * D);
        const int4* p1 = (const int4*)(hbf + (size_t)s1 * D);
        int4 r0a = p0[2 * q], r0b = p0[2 * q + 1];
        int4 r1a = p1[2 * q], r1b = p1[2 * q + 1];
        ACC8(r0a, r0b, w0)
        wsum += w0;
        ACC8(r1a, r1b, w1)
        wsum += w1;
      }
      for (; i < end; ++i) {
        long long e0 = __builtin_nontemporal_load(epair + i);
        int s0 = (int)(e0 & 0xFFFFFFFFll);
        float w0 = __int_as_float((int)(e0 >> 32));
        const int4* p0 = (const int4*)(hbf + (size_t)s0 * D);
        int4 r0a = p0[2 * q], r0b = p0[2 * q + 1];
        ACC8(r0a, r0b, w0)
        wsum += w0;
      }
      // own term: fp32 x for layer 0 (single pass), bf16 after
      if (first) {
        const float4* own = (const float4*)(x0 + (size_t)n * D) + q * 4;
        float4 o0 = own[0], o1 = own[1], o2 = own[2], o3 = own[3];
        a0.x += o0.x; a0.y += o0.y; a0.z += o0.z; a0.w += o0.w;
        a1.x += o1.x; a1.y += o1.y; a1.z += o1.z; a1.w += o1.w;
        a2.x += o2.x; a2.y += o2.y; a2.z += o2.z; a2.w += o2.w;
        a3.x += o3.x; a3.y += o3.y; a3.z += o3.z; a3.w += o3.w;
      } else {
        const int4* hp = (const int4*)(hbf + (size_t)n * D);
        int4 c0 = hp[2 * q], c1 = hp[2 * q + 1];
        a0.x += bflo(c0.x); a0.y += bfhi(c0.x);
        a0.z += bflo(c0.y); a0.w += bfhi(c0.y);
        a1.x += bflo(c0.z); a1.y += bfhi(c0.z);
        a1.z += bflo(c0.w); a1.w += bfhi(c0.w);
        a2.x += bflo(c1.x); a2.y += bfhi(c1.x);
        a2.z += bflo(c1.y); a2.w += bfhi(c1.y);
        a3.x += bflo(c1.z); a3.y += bfhi(c1.z);
        a3.z += bflo(c1.w); a3.w += bfhi(c1.w);
      }
    }
    float* zr = &zin[nl * 65 + q * 16];
    *(float4*)(zr + 0) = a0;
    *(float4*)(zr + 4) = a1;
    *(float4*)(zr + 8) = a2;
    *(float4*)(zr + 12) = a3;
    if (q == 0) wsumS[nl] = wsum;
  }
  __syncthreads();

  // deferred-BN affine pass over the z-tile
  if (!first) {
#pragma unroll
    for (int pass = 0; pass < 4; ++pass) {
      int idx = pass * 1024 + t * 4;
      int r = idx >> 6, c = idx & 63;
      float wp1 = 1.f + wsumS[r];
      float4 z = *(float4*)&zin[r * 65 + c];
      z.x = fmaf(z.x, scA[c + 0], sbA[c + 0] * wp1);
      z.y = fmaf(z.y, scA[c + 1], sbA[c + 1] * wp1);
      z.z = fmaf(z.z, scA[c + 2], sbA[c + 2] * wp1);
      z.w = fmaf(z.w, scA[c + 3], sbA[c + 3] * wp1);
      *(float4*)&zin[r * 65 + c] = z;
    }
    __syncthreads();
  }

#define GEMM_HALF(ACC, KBASE)                                                 \
  _Pragma("unroll 2") for (int kc = 0; kc < 8; ++kc) {                        \
    float4 zv[4], wv[4];                                                      \
    _Pragma("unroll") for (int i = 0; i < 4; ++i)                             \
        zv[i] = *(float4*)&zin[(nr * 4 + i) * 65 + ((KBASE) + kc) * 4];       \
    _Pragma("unroll") for (int kk = 0; kk < 4; ++kk)                          \
        wv[kk] = *(float4*)&sW[(kc * 4 + kk) * 64 + fc * 4];                  \
    _Pragma("unroll") for (int i = 0; i < 4; ++i) {                           \
      ACC[i].x = fmaf(zv[i].x, wv[0].x, ACC[i].x);                            \
      ACC[i].y = fmaf(zv[i].x, wv[0].y, ACC[i].y);                            \
      ACC[i].z = fmaf(zv[i].x, wv[0].z, ACC[i].z);                            \
      ACC[i].w = fmaf(zv[i].x, wv[0].w, ACC[i].w);                            \
      ACC[i].x = fmaf(zv[i].y, wv[1].x, ACC[i].x);                            \
      ACC[i].y = fmaf(zv[i].y, wv[1].y, ACC[i].y);                            \
      ACC[i].z = fmaf(zv[i].y, wv[1].z, ACC[i].z);                            \
      ACC[i].w = fmaf(zv[i].y, wv[1].w, ACC[i].w);                            \
      ACC[i].x = fmaf(zv[i].z, wv[2].x, ACC[i].x);                            \
      ACC[i].y = fmaf(zv[i].z, wv[2].y, ACC[i].y);                            \
      ACC[i].z = fmaf(zv[i].z, wv[2].z, ACC[i].z);                            \
      ACC[i].w = fmaf(zv[i].z, wv[2].w, ACC[i].w);                            \
      ACC[i].x = fmaf(zv[i].w, wv[3].x, ACC[i].x);                            \
      ACC[i].y = fmaf(zv[i].w, wv[3].y, ACC[i].y);                            \
      ACC[i].z = fmaf(zv[i].w, wv[3].z, ACC[i].z);                            \
      ACC[i].w = fmaf(zv[i].w, wv[3].w, ACC[i].w);                            \
    }                                                                         \
  }

#define RELU4(ACC)                                                            \
  _Pragma("unroll") for (int i = 0; i < 4; ++i) {                             \
    ACC[i].x = fmaxf(ACC[i].x, 0.f);                                          \
    ACC[i].y = fmaxf(ACC[i].y, 0.f);                                          \
    ACC[i].z = fmaxf(ACC[i].z, 0.f);                                          \
    ACC[i].w = fmaxf(ACC[i].w, 0.f);                                          \
  }

  // ---- GEMM1 ----
  float4 acc[4];
  {
    float4 bias = *(float4*)&sb[fc * 4];
#pragma unroll
    for (int i = 0; i < 4; ++i) acc[i] = bias;
  }
  GEMM_HALF(acc, 0)
  __syncthreads();
  for (int i = t; i < 2048; i += 256) sW[i] = W1[2048 + i];
  __syncthreads();
  GEMM_HALF(acc, 8)
  RELU4(acc)
  __syncthreads();

  // write intermediate, stage W2 rows 0..31 + b2
#pragma unroll
  for (int i = 0; i < 4; ++i) *(float4*)&zin[(nr * 4 + i) * 65 + fc * 4] = acc[i];
  for (int i = t; i < 2048; i += 256) sW[i] = W2[i];
  if (t < 64) sb[t] = b2[t];
  __syncthreads();

  // ---- GEMM2 ----
  float4 acc2[4];
  {
    float4 bias = *(float4*)&sb[fc * 4];
#pragma unroll
    for (int i = 0; i < 4; ++i) acc2[i] = bias;
  }
  GEMM_HALF(acc2, 0)
  __syncthreads();
  for (int i = t; i < 2048; i += 256) sW[i] = W2[2048 + i];
  __syncthreads();
  GEMM_HALF(acc2, 8)
  RELU4(acc2)
  __syncthreads();  // zin (intermediate) reads done -> safe to overwrite

  // bf16 NT store (keep src window L2-resident) + stats partials +
  // stash output tile in zin for pooling
  float4 s4 = {0.f, 0.f, 0.f, 0.f}, q4 = {0.f, 0.f, 0.f, 0.f};
#pragma unroll
  for (int i = 0; i < 4; ++i) {
    int n = nb + nr * 4 + i;
    *(float4*)&zin[(nr * 4 + i) * 65 + fc * 4] = acc2[i];
    if (n < NN) {
      unsigned long long ob = (unsigned long long)bf16rne(acc2[i].x) |
                              ((unsigned long long)bf16rne(acc2[i].y) << 16) |
                              ((unsigned long long)bf16rne(acc2[i].z) << 32) |
                              ((unsigned long long)bf16rne(acc2[i].w) << 48);
      __builtin_nontemporal_store(
          ob, (unsigned long long*)(gbf + (size_t)n * D + fc * 4));
      s4.x += acc2[i].x; s4.y += acc2[i].y; s4.z += acc2[i].z; s4.w += acc2[i].w;
      q4.x = fmaf(acc2[i].x, acc2[i].x, q4.x);
      q4.y = fmaf(acc2[i].y, acc2[i].y, q4.y);
      q4.z = fmaf(acc2[i].z, acc2[i].z, q4.z);
      q4.w = fmaf(acc2[i].w, acc2[i].w, q4.w);
    }
  }
  __syncthreads();  // zin holds the f32 output tile

  // ---- fused per-graph mean-pool partials (sorted batch segments) ----
  {
    const int nbend = (nb + 64 < NN) ? nb + 64 : NN;
    const int gs = batch_[nb];
    const int ge = batch_[nbend - 1];
    const int c = t & 63, qr = t >> 6;
    for (int g = gs; g <= ge; ++g) {
      int a = gstart_[g];
      int b = gstart_[g + 1];
      a = (a > nb) ? a - nb : 0;
      b = (b < nbend) ? b - nb : nbend - nb;
      float p = 0.f;
      for (int r = a + qr; r < b; r += 4) p += zin[r * 65 + c];
      psum[t] = p;
      __syncthreads();
      if (t < 64) {
        float tot = psum[t] + psum[t + 64] + psum[t + 128] + psum[t + 192];
        unsafeAtomicAdd(&pooledraw[(size_t)g * EMBD + layer * D + t], tot);
      }
      __syncthreads();
    }
  }

  // ---- BN-stats: shfl reduce + LDS combine (zin now dead) ----
#pragma unroll
  for (int m = 16; m <= 32; m <<= 1) {
    s4.x += __shfl_xor(s4.x, m, 64); s4.y += __shfl_xor(s4.y, m, 64);
    s4.z += __shfl_xor(s4.z, m, 64); s4.w += __shfl_xor(s4.w, m, 64);
    q4.x += __shfl_xor(q4.x, m, 64); q4.y += __shfl_xor(q4.y, m, 64);
    q4.z += __shfl_xor(q4.z, m, 64); q4.w += __shfl_xor(q4.w, m, 64);
  }
  int wv_ = t >> 6;
  if ((t & 63) < 16) {
    *(float4*)&zin[wv_ * 64 + fc * 4] = s4;        // sSf = zin[0..255]
    *(float4*)&zin[256 + wv_ * 64 + fc * 4] = q4;  // sQf = zin[256..511]
  }
  __syncthreads();
  if (t < 64) {
    float S = zin[t] + zin[64 + t] + zin[128 + t] + zin[192 + t];
    float Q = zin[256 + t] + zin[320 + t] + zin[384 + t] + zin[448 + t];
    unsafeAtomicAdd(&statsL[t], S);
    unsafeAtomicAdd(&statsL[64 + t], Q);
  }
#undef GEMM_HALF
#undef RELU4
}

// ------- projection head (pool-divide + all 5 layers' BN affine) ----------
__global__ __launch_bounds__(EMBD) void k_proj(const float* __restrict__ pooledraw,
                                               const int* __restrict__ gstart,
                                               const float* __restrict__ stats,
                                               const float* __restrict__ gammas,
                                               const float* __restrict__ betas,
                                               const float* __restrict__ pW1,
                                               const float* __restrict__ pb1,
                                               const float* __restrict__ pW2,
                                               const float* __restrict__ pb2,
                                               float* __restrict__ out) {
  __shared__ float row[EMBD];
  __shared__ float y1[EMBD];
  int g = blockIdx.x, j = threadIdx.x;
  {
    int L = j >> 6, f = j & 63;
    float m = stats[L * 128 + f] * (1.f / NN);
    float v = fmaxf(stats[L * 128 + 64 + f] * (1.f / NN) - m * m, 0.f);
    float sc = gammas[L * D + f] * rsqrtf(v + BN_EPS);
    float sb = betas[L * D + f] - m * sc;
    int cnt = gstart[g + 1] - gstart[g];
    float inv = 1.0f / (float)(cnt > 1 ? cnt : 1);
    row[j] = fmaf(pooledraw[(size_t)g * EMBD + j] * inv, sc, sb);
  }
  __syncthreads();
  float acc = pb1[j];
#pragma unroll 4
  for (int k = 0; k < EMBD; ++k) acc = fmaf(row[k], pW1[(size_t)k * EMBD + j], acc);
  y1[j] = fmaxf(acc, 0.f);
  __syncthreads();
  acc = pb2[j];
#pragma unroll 4
  for (int k = 0; k < EMBD; ++k) acc = fmaf(y1[k], pW2[(size_t)k * EMBD + j], acc);
  out[(size_t)g * EMBD + j] = acc;
}

extern "C" void kernel_launch(void* const* d_in, const int* in_sizes, int n_in,
                              void* d_out, int out_size, void* d_ws, size_t ws_size,
                              hipStream_t stream) {
  const float* x = (const float*)d_in[0];
  const int* ei = (const int*)d_in[1];
  const float* ew = (const float*)d_in[2];
  const int* batch = (const int*)d_in[3];
  const float* W1s = (const float*)d_in[4];
  const float* b1s = (const float*)d_in[5];
  const float* W2s = (const float*)d_in[6];
  const float* b2s = (const float*)d_in[7];
  const float* gammas = (const float*)d_in[8];
  const float* betas = (const float*)d_in[9];
  const float* pW1 = (const float*)d_in[10];
  const float* pb1 = (const float*)d_in[11];
  const float* pW2 = (const float*)d_in[12];
  const float* pb2 = (const float*)d_in[13];
  const int* srcv = ei;
  const int* dstv = ei + NE;

  char* ws = (char*)d_ws;
  float* stats = (float*)ws;                             // NL*128
  float* pooledraw = stats + NL * 128;                   // NG*EMBD (sums)
  int* gstart = (int*)(pooledraw + (size_t)NG * EMBD);   // NG+1
  int* row_ptr = gstart + NG + 1;                        // M2+1
  int* table = row_ptr + M2 + 1;                         // TBL
  int* bsums = table + TBL;                              // SCANT_NB
  long long* tmp = (long long*)(bsums + SCANT_NB + 1);   // NE (8B)
  long long* epair = tmp + NE;                           // NE (8B)
  unsigned short* hbfA = (unsigned short*)(epair + NE);  // NN*D bf16
  unsigned short* hbfB = hbfA + (size_t)NN * D;          // NN*D bf16

  // ---- CSR build (two-level counting sort) + graph bounds + zeroing ----
  hipMemsetAsync(stats, 0,
                 (NL * 128 + (size_t)NG * EMBD) * sizeof(float), stream);
  k_passA<<<NCH, 256, 0, stream>>>(dstv, table);
  k_scanT1<<<SCANT_NB, 256, 0, stream>>>(table, bsums);
  k_scanT2<<<1, 512, 0, stream>>>(bsums);
  k_scanT3<<<SCANT_NB, 256, 0, stream>>>(table, bsums);
  k_passB<<<NCH, 256, 0, stream>>>(srcv, dstv, ew, table, tmp);
  k_passC<<<NBK, 512, 0, stream>>>(tmp, table, row_ptr, epair);
  k_gbound<<<SCAN_NB, 256, 0, stream>>>(batch, gstart);
  k_cvt<<<(NN * 16 + 255) / 256, 256, 0, stream>>>(x, hbfA);

  unsigned short* bfin = hbfA;
  unsigned short* bfout = hbfB;
  for (int L = 0; L < NL; ++L) {
    k_gin<<<GIN_NB, 256, 0, stream>>>(x, bfin, bfout, row_ptr, epair,
                                      batch, gstart, pooledraw, L,
                                      W1s + L * D * D, b1s + L * D,
                                      W2s + L * D * D, b2s + L * D,
                                      stats + (L > 0 ? (L - 1) * 128 : 0),
                                      gammas + (L > 0 ? (L - 1) * D : 0),
                                      betas + (L > 0 ? (L - 1) * D : 0),
                                      L == 0 ? 1 : 0,
                                      stats + L * 128);
    unsigned short* tmpb = bfin;
    bfin = bfout;
    bfout = tmpb;
  }
  k_proj<<<NG, EMBD, 0, stream>>>(pooledraw, gstart, stats, gammas, betas,
                                  pW1, pb1, pW2, pb2, (float*)d_out);
}